// Round 5
// baseline (384.380 us; speedup 1.0000x reference)
//
#include <hip/hip_runtime.h>
#include <type_traits>
#include <utility>

typedef unsigned short u16;
typedef unsigned int u32;
typedef short short8 __attribute__((ext_vector_type(8)));
typedef __bf16 bf16x8 __attribute__((ext_vector_type(8)));
typedef float floatx4 __attribute__((ext_vector_type(4)));

// ---- MFMA wrapper robust to either builtin signature (short8 vs v8bf16) ----
template <typename V, typename = void> struct MfmaTakes : std::false_type {};
template <typename V>
struct MfmaTakes<V, std::void_t<decltype(__builtin_amdgcn_mfma_f32_16x16x32_bf16(
    std::declval<V>(), std::declval<V>(), std::declval<floatx4>(), 0, 0, 0))>>
    : std::true_type {};

template <typename V>
__device__ __forceinline__ floatx4 mfma_impl(V a, V b, floatx4 c, std::true_type) {
  return __builtin_amdgcn_mfma_f32_16x16x32_bf16(a, b, c, 0, 0, 0);
}
template <typename V>
__device__ __forceinline__ floatx4 mfma_impl(V a, V b, floatx4 c, std::false_type) {
  return __builtin_amdgcn_mfma_f32_16x16x32_bf16(
      __builtin_bit_cast(bf16x8, a), __builtin_bit_cast(bf16x8, b), c, 0, 0, 0);
}
__device__ __forceinline__ floatx4 MFMA16(short8 a, short8 b, floatx4 c) {
  return mfma_impl<short8>(a, b, c, MfmaTakes<short8>{});
}

__device__ __forceinline__ u16 f2bf(float f) {
  union { float f; unsigned u; } x; x.f = f;
  unsigned r = (x.u + 0x7fffu + ((x.u >> 16) & 1u)) >> 16;
  return (u16)r;
}
__device__ __forceinline__ float bf2f(u16 v) {
  union { unsigned u; float f; } x; x.u = ((unsigned)v) << 16; return x.f;
}
__device__ __forceinline__ u32 packbf(float lo, float hi) {
  return (__float_as_uint(hi) & 0xffff0000u) | (__float_as_uint(lo) >> 16);
}

// ---- async global->LDS staging (16B/lane), fallback to vector copy ----
#if defined(__has_builtin)
#if __has_builtin(__builtin_amdgcn_global_load_lds)
#define HAS_GLLDS 1
#endif
#endif
__device__ __forceinline__ void stage16(const u16* g, u16* lbase, int lane) {
#ifdef HAS_GLLDS
  __builtin_amdgcn_global_load_lds(
      (__attribute__((address_space(1))) void*)(g),
      (__attribute__((address_space(3))) void*)(lbase), 16, 0, 0);
#else
  *(uint4*)(lbase + lane * 8) = *(const uint4*)g;
#endif
}

// ---------------- prep: x->bf16, concat W->bf16, out_w->bf16, lambda weights
__global__ __launch_bounds__(256) void prep_kernel(
    const float* __restrict__ x, const float* __restrict__ qw,
    const float* __restrict__ kw, const float* __restrict__ vw,
    const float* __restrict__ outw, const float* __restrict__ lam,
    u16* __restrict__ xb, u16* __restrict__ wcat, u16* __restrict__ outwb,
    float* __restrict__ lwbuf) {
  size_t gid = (size_t)blockIdx.x * 256 + threadIdx.x;
  if (gid == 0) {
    float s0 = 1.f / (1.f + expf(-lam[0]));
    float s1 = 1.f / (1.f + expf(-lam[1]));
    float s2 = 1.f / (1.f + expf(-lam[2]));
    float mean = (s0 + s1 + s2) * (1.f / 3.f);
    float d0 = s0 - mean, d1 = s1 - mean, d2 = s2 - mean;
    float var = (d0 * d0 + d1 * d1 + d2 * d2) * (1.f / 3.f);
    float r = rsqrtf(var + 1e-5f);
    lwbuf[0] = d0 * r; lwbuf[1] = d1 * r; lwbuf[2] = d2 * r;
  }
  if (gid < 524288) {
    float4 v = ((const float4*)x)[gid];
    ushort4 o; o.x = f2bf(v.x); o.y = f2bf(v.y); o.z = f2bf(v.z); o.w = f2bf(v.w);
    ((ushort4*)xb)[gid] = o;
    return;
  }
  size_t g2 = gid - 524288;
  if (g2 < 1572864) {  // wcat rows: [layer][q(1024)|k(512)|v(512)] x 1024 cols
    int col4 = (int)(g2 & 255);
    int n = (int)(g2 >> 8);
    int layer = n >> 11, r = n & 2047;
    const float* srcrow;
    if (r < 1024) srcrow = qw + ((size_t)(layer * 1024 + r) << 10);
    else if (r < 1536) srcrow = kw + ((size_t)(layer * 512 + (r - 1024)) << 10);
    else srcrow = vw + ((size_t)(layer * 512 + (r - 1536)) << 10);
    float4 v = ((const float4*)srcrow)[col4];
    ushort4 o; o.x = f2bf(v.x); o.y = f2bf(v.y); o.z = f2bf(v.z); o.w = f2bf(v.w);
    ((ushort4*)wcat)[g2] = o;
    return;
  }
  size_t g3 = g2 - 1572864;
  if (g3 < 262144) {
    float4 v = ((const float4*)outw)[g3];
    ushort4 o; o.x = f2bf(v.x); o.y = f2bf(v.y); o.z = f2bf(v.z); o.w = f2bf(v.w);
    ((ushort4*)outwb)[g3] = o;
  }
}

// ---------------- GEMM 128x128 tile with global_load_lds staging (m97-style)
__global__ __launch_bounds__(256) void gemm128(
    const u16* __restrict__ A, const u16* __restrict__ Bw,
    void* __restrict__ Cp, int N, int K, int obf16) {
  __shared__ u16 As[128][64];
  __shared__ u16 Bs[128][64];
  const int bm = blockIdx.x, bn = blockIdx.y;
  const int tid = threadIdx.x;
  const int wave = tid >> 6, lane = tid & 63;
  const int quad = lane >> 4, l16 = lane & 15;
  const int wm = wave & 1, wn = wave >> 1;
  const int srow = lane >> 3, skc = (lane & 7) * 8;
  floatx4 acc[4][4];
#pragma unroll
  for (int i = 0; i < 4; i++)
#pragma unroll
    for (int j = 0; j < 4; j++) { acc[i][j][0] = 0.f; acc[i][j][1] = 0.f; acc[i][j][2] = 0.f; acc[i][j][3] = 0.f; }
  const u16* Abase = A + (size_t)(bm * 128) * K;
  const u16* Bbase = Bw + (size_t)(bn * 128) * K;
  for (int k0 = 0; k0 < K; k0 += 64) {
    __syncthreads();
#pragma unroll
    for (int i = 0; i < 4; i++) {
      int ch = wave * 4 + i;
      stage16(Abase + (size_t)(ch * 8 + srow) * K + k0 + skc, &As[ch * 8][0], lane);
      stage16(Bbase + (size_t)(ch * 8 + srow) * K + k0 + skc, &Bs[ch * 8][0], lane);
    }
    __syncthreads();
#pragma unroll
    for (int kf = 0; kf < 2; kf++) {
      short8 af[4], bf[4];
#pragma unroll
      for (int mi = 0; mi < 4; mi++)
        af[mi] = *(const short8*)(&As[wm * 64 + mi * 16 + l16][kf * 32 + quad * 8]);
#pragma unroll
      for (int ni = 0; ni < 4; ni++)
        bf[ni] = *(const short8*)(&Bs[wn * 64 + ni * 16 + l16][kf * 32 + quad * 8]);
#pragma unroll
      for (int mi = 0; mi < 4; mi++)
#pragma unroll
        for (int ni = 0; ni < 4; ni++)
          acc[mi][ni] = MFMA16(af[mi], bf[ni], acc[mi][ni]);
    }
  }
  float* Cf = (float*)Cp;
  u16* Cb = (u16*)Cp;
#pragma unroll
  for (int mi = 0; mi < 4; mi++)
#pragma unroll
    for (int ni = 0; ni < 4; ni++)
#pragma unroll
      for (int r = 0; r < 4; r++) {
        int row = bm * 128 + wm * 64 + mi * 16 + quad * 4 + r;
        int col = bn * 128 + wn * 64 + ni * 16 + l16;
        if (obf16) Cb[(size_t)row * N + col] = f2bf(acc[mi][ni][r]);
        else Cf[(size_t)row * N + col] = acc[mi][ni][r];
      }
}

// ---------------- small GEMM (64x64 tile) for the out-projection
__global__ __launch_bounds__(256) void gemm_bt(
    const u16* __restrict__ A, const u16* __restrict__ Bw,
    float* __restrict__ C, int N, int K) {
  __shared__ u16 As[64][72];
  __shared__ u16 Bs[64][72];
  const int bm = blockIdx.x, bn = blockIdx.y;
  const int tid = threadIdx.x;
  const int wave = tid >> 6, lane = tid & 63;
  const int quad = lane >> 4, l16 = lane & 15;
  const int lr = tid >> 2, lc = (tid & 3) << 4;
  floatx4 acc[4];
#pragma unroll
  for (int i = 0; i < 4; i++) { acc[i][0] = 0.f; acc[i][1] = 0.f; acc[i][2] = 0.f; acc[i][3] = 0.f; }
  const u16* Arow = A + (size_t)(bm * 64 + lr) * K;
  const u16* Brow = Bw + (size_t)(bn * 64 + lr) * K;
  for (int k0 = 0; k0 < K; k0 += 64) {
    __syncthreads();
    *(uint4*)(&As[lr][lc])     = *(const uint4*)(Arow + k0 + lc);
    *(uint4*)(&As[lr][lc + 8]) = *(const uint4*)(Arow + k0 + lc + 8);
    *(uint4*)(&Bs[lr][lc])     = *(const uint4*)(Brow + k0 + lc);
    *(uint4*)(&Bs[lr][lc + 8]) = *(const uint4*)(Brow + k0 + lc + 8);
    __syncthreads();
    const int mrow = wave * 16 + l16;
    short8 a0 = *(const short8*)(&As[mrow][quad * 8]);
    short8 a1 = *(const short8*)(&As[mrow][32 + quad * 8]);
#pragma unroll
    for (int ns = 0; ns < 4; ns++) {
      short8 b0 = *(const short8*)(&Bs[ns * 16 + l16][quad * 8]);
      short8 b1 = *(const short8*)(&Bs[ns * 16 + l16][32 + quad * 8]);
      acc[ns] = MFMA16(a0, b0, acc[ns]);
      acc[ns] = MFMA16(a1, b1, acc[ns]);
    }
  }
#pragma unroll
  for (int ns = 0; ns < 4; ns++)
#pragma unroll
    for (int r = 0; r < 4; r++) {
      int row = bm * 64 + wave * 16 + quad * 4 + r;
      int col = bn * 64 + ns * 16 + l16;
      C[(size_t)row * N + col] = acc[ns][r];
    }
}

// ---------------- fused reshape: RoPE Q (x0.125) + RoPE K + V transpose
__global__ __launch_bounds__(256) void reshape_kernel(
    const u16* __restrict__ qkvb, const float* __restrict__ cosb,
    const float* __restrict__ sinb, u16* __restrict__ qr,
    u16* __restrict__ kr, u16* __restrict__ vtg) {
  __shared__ u16 T[64][72];
  const int bid = blockIdx.x, tid = threadIdx.x;
  union U8 { uint4 v; u16 s[8]; };
  union F8 { float4 v[2]; float f[8]; };
  if (bid < 2304) {
    unsigned gid = (unsigned)bid * 256 + tid;
    if (gid < 393216u) {  // Q
      int d8 = gid & 3, t = (gid >> 2) & 1023, h = (gid >> 12) & 15;
      int b = (gid >> 16) & 1, layer = gid >> 17;
      size_t src = (size_t)(b * 1024 + t) * 6144 + layer * 2048 + h * 64 + d8 * 8;
      U8 xa, xc; xa.v = *(const uint4*)(qkvb + src); xc.v = *(const uint4*)(qkvb + src + 32);
      F8 C, S;
      const float4* cp = (const float4*)(cosb + (size_t)t * 32 + d8 * 8);
      const float4* sp = (const float4*)(sinb + (size_t)t * 32 + d8 * 8);
      C.v[0] = cp[0]; C.v[1] = cp[1]; S.v[0] = sp[0]; S.v[1] = sp[1];
      U8 o1, o2;
#pragma unroll
      for (int j = 0; j < 8; j++) {
        float x1 = bf2f(xa.s[j]), x2 = bf2f(xc.s[j]);
        o1.s[j] = f2bf((x1 * C.f[j] - x2 * S.f[j]) * 0.125f);  // fold HD^-0.5
        o2.s[j] = f2bf((x2 * C.f[j] + x1 * S.f[j]) * 0.125f);
      }
      size_t dst = ((((size_t)layer * 2 + b) * 16 + h) * 1024 + t) * 64 + d8 * 8;
      *(uint4*)(qr + dst) = o1.v;
      *(uint4*)(qr + dst + 32) = o2.v;
      return;
    }
    unsigned g2 = gid - 393216u;
    if (g2 < 196608u) {  // K
      int d8 = g2 & 3, t = (g2 >> 2) & 1023, h = (g2 >> 12) & 7;
      int b = (g2 >> 15) & 1, layer = g2 >> 16;
      int pos = layer * 1024 + t;  // layer-j keys sit at offset j*T
      size_t src = (size_t)(b * 1024 + t) * 6144 + layer * 2048 + 1024 + h * 64 + d8 * 8;
      U8 xa, xc; xa.v = *(const uint4*)(qkvb + src); xc.v = *(const uint4*)(qkvb + src + 32);
      F8 C, S;
      const float4* cp = (const float4*)(cosb + (size_t)pos * 32 + d8 * 8);
      const float4* sp = (const float4*)(sinb + (size_t)pos * 32 + d8 * 8);
      C.v[0] = cp[0]; C.v[1] = cp[1]; S.v[0] = sp[0]; S.v[1] = sp[1];
      U8 o1, o2;
#pragma unroll
      for (int j = 0; j < 8; j++) {
        float x1 = bf2f(xa.s[j]), x2 = bf2f(xc.s[j]);
        o1.s[j] = f2bf(x1 * C.f[j] - x2 * S.f[j]);
        o2.s[j] = f2bf(x2 * C.f[j] + x1 * S.f[j]);
      }
      size_t dst = (((size_t)b * 8 + h) * 3072 + pos) * 64 + d8 * 8;
      *(uint4*)(kr + dst) = o1.v;
      *(uint4*)(kr + dst + 32) = o2.v;
    }
    return;
  }
  // V transpose -> vt [B][HKV][64][3072]
  const int b2 = bid - 2304;
  const int xt = b2 & 15;
  const int y = b2 >> 4;
  const int layer = y >> 4, b = (y >> 3) & 1, h = y & 7;
  const int t0 = xt * 64;
  {
    const int p = tid >> 2, dc = (tid & 3) * 16;
    const u16* src = qkvb + (size_t)(b * 1024 + t0 + p) * 6144 + layer * 2048 + 1536 + h * 64 + dc;
    U8 u0, u1;
    u0.v = *(const uint4*)(src);
    u1.v = *(const uint4*)(src + 8);
#pragma unroll
    for (int j = 0; j < 8; j++) { T[dc + j][p] = u0.s[j]; T[dc + 8 + j][p] = u1.s[j]; }
  }
  __syncthreads();
  {
    const int d = tid >> 2, pc = (tid & 3) * 16;
    u16* dst = vtg + ((size_t)((b * 8 + h) * 64 + d)) * 3072 + layer * 1024 + t0 + pc;
    *(uint4*)(dst) = *(const uint4*)(&T[d][pc]);
    *(uint4*)(dst + 8) = *(const uint4*)(&T[d][pc + 8]);
  }
}

// ---------------- attention v3: BARRIER-FREE K-loop.
// K and V^T fragments are A-operands contiguous in global memory -> loaded
// directly (L1/L2 serve the 4-wave reuse); the only LDS is the per-wave P
// round-trip (no __syncthreads anywhere in the loop). S^T orientation as r4.
// Epilogue transposes O^T->O through a per-wave LDS tile and writes row-major
// slots [z][b][t][h*64+d] so fused_norm reads coalesced.
__global__ __launch_bounds__(256) void attn_v3(
    const u16* __restrict__ qr, const u16* __restrict__ kr,
    const u16* __restrict__ vt, float* __restrict__ obS,
    float* __restrict__ lbufp) {
  __shared__ u16 Pw[4][2][16][72];  // [wave][nt][q][key]; reused as fp32 in epilogue
  const unsigned z = blockIdx.z;
  const int lay = (0x012221u >> (z * 4)) & 0xF;  // z: (1,0)(2,0)(2,1)(2,2)(1,1)(0,0)
  const int c   = (0x012100u >> (z * 4)) & 0xF;
  const int qtile = 7 - (int)blockIdx.x;
  const int bh = blockIdx.y;
  const int b = bh >> 4, h = bh & 15, hk = h >> 1;
  const int tid = threadIdx.x, wave = tid >> 6, lane = tid & 63;
  const int quad = lane >> 4, l16 = lane & 15;
  const int kt0 = c * 16;
  const int kt1 = (c == lay) ? (lay * 16 + 2 * qtile + 2) : (kt0 + 16);
  const int maskkt = lay * 16 + 2 * qtile;
  const int qeffbase = lay * 1024 + qtile * 128 + wave * 32;
  const u16* qpb = qr + ((((size_t)lay * 2 + b) * 16 + h) * 1024
                         + qtile * 128 + wave * 32 + l16) * 64 + quad * 8;
  short8 qf[2][2];
  qf[0][0] = *(const short8*)(qpb);
  qf[0][1] = *(const short8*)(qpb + 32);
  qf[1][0] = *(const short8*)(qpb + 1024);
  qf[1][1] = *(const short8*)(qpb + 1056);
  const short8 ones = {16256, 16256, 16256, 16256, 16256, 16256, 16256, 16256};
  floatx4 oacc[2][4];
#pragma unroll
  for (int nt = 0; nt < 2; nt++)
#pragma unroll
    for (int dt = 0; dt < 4; dt++) { oacc[nt][dt][0] = 0.f; oacc[nt][dt][1] = 0.f; oacc[nt][dt][2] = 0.f; oacc[nt][dt][3] = 0.f; }
  floatx4 lacc[2];
  lacc[0][0] = 0.f; lacc[0][1] = 0.f; lacc[0][2] = 0.f; lacc[0][3] = 0.f;
  lacc[1] = lacc[0];
  const u16* kbase = kr + (size_t)(b * 8 + hk) * 3072 * 64 + quad * 8;   // + pos*64
  const u16* vbase = vt + (size_t)(b * 8 + hk) * 64 * 3072 + quad * 8;   // + d*3072 + pos
  for (int kt = kt0; kt < kt1; kt++) {
    const bool needmask = (kt >= maskkt);
    // S^T = K Q^T per 16-key tile; exp+pack immediately (keeps regs low)
#pragma unroll
    for (int mt = 0; mt < 4; mt++) {
      const u16* kp = kbase + (size_t)(kt * 64 + mt * 16 + l16) * 64;
      short8 kfa = *(const short8*)(kp);
      short8 kfb = *(const short8*)(kp + 32);
      const int keyb = kt * 64 + mt * 16 + quad * 4;
#pragma unroll
      for (int nt = 0; nt < 2; nt++) {
        floatx4 s; s[0] = 0.f; s[1] = 0.f; s[2] = 0.f; s[3] = 0.f;
        s = MFMA16(kfa, qf[nt][0], s);
        s = MFMA16(kfb, qf[nt][1], s);
        float p0 = __expf(s[0]), p1 = __expf(s[1]);
        float p2 = __expf(s[2]), p3 = __expf(s[3]);
        if (needmask) {
          int qpos = qeffbase + nt * 16 + l16;
          if (keyb + 0 > qpos) p0 = 0.f;
          if (keyb + 1 > qpos) p1 = 0.f;
          if (keyb + 2 > qpos) p2 = 0.f;
          if (keyb + 3 > qpos) p3 = 0.f;
        }
        uint2 st; st.x = packbf(p0, p1); st.y = packbf(p2, p3);
        *(uint2*)(&Pw[wave][nt][l16][mt * 16 + quad * 4]) = st;
      }
    }
    // O^T += V^T P ; l += col-sums (per-wave LDS: in-order, no barrier)
#pragma unroll
    for (int kc = 0; kc < 2; kc++) {
      short8 pf0 = *(const short8*)(&Pw[wave][0][l16][kc * 32 + quad * 8]);
      short8 pf1 = *(const short8*)(&Pw[wave][1][l16][kc * 32 + quad * 8]);
      lacc[0] = MFMA16(ones, pf0, lacc[0]);
      lacc[1] = MFMA16(ones, pf1, lacc[1]);
#pragma unroll
      for (int dt = 0; dt < 4; dt++) {
        const u16* vp = vbase + (size_t)(dt * 16 + l16) * 3072 + kt * 64 + kc * 32;
        short8 vf = *(const short8*)(vp);
        oacc[0][dt] = MFMA16(vf, pf0, oacc[0][dt]);
        oacc[1][dt] = MFMA16(vf, pf1, oacc[1][dt]);
      }
    }
  }
  // epilogue: O^T (d=row, t=col) -> row-major [t][d] via per-wave LDS tile
  float* Pf = (float*)(&Pw[wave][0][0][0]);  // 4608 B/wave >= 2*16*20*4
  const int tt = lane >> 2, dd = (lane & 3) << 2;
#pragma unroll
  for (int nt = 0; nt < 2; nt++) {
    int t = qtile * 128 + wave * 32 + nt * 16 + l16;
    if (quad == 0)
      lbufp[((size_t)z * 2048 + b * 1024 + t) * 16 + h] = lacc[nt][0];
    int t2 = qtile * 128 + wave * 32 + nt * 16 + tt;
    float* orow = obS + ((size_t)(z * 2 + b) * 1024 + t2) * 1024 + h * 64 + dd;
#pragma unroll
    for (int dt = 0; dt < 4; dt++) {
      *(floatx4*)(&Pf[nt * 320 + l16 * 20 + quad * 4]) = oacc[nt][dt];  // [t][d] tile
      floatx4 val = *(const floatx4*)(&Pf[nt * 320 + tt * 20 + dd]);    // wave-ordered
      *(floatx4*)(orow + dt * 16) = val;
    }
  }
}

// ---------------- fused: slot-sum (coalesced rows), /l, rmsnorm chain
__device__ __forceinline__ float block_sum(float v, float* red) {
  v += __shfl_xor(v, 32); v += __shfl_xor(v, 16); v += __shfl_xor(v, 8);
  v += __shfl_xor(v, 4);  v += __shfl_xor(v, 2);  v += __shfl_xor(v, 1);
  __syncthreads();
  if ((threadIdx.x & 63) == 0) red[threadIdx.x >> 6] = v;
  __syncthreads();
  return red[0] + red[1] + red[2] + red[3];
}

__global__ __launch_bounds__(256) void fused_norm(
    const float* __restrict__ obS, const float* __restrict__ lbufp,
    const float* __restrict__ x, const float* __restrict__ lnw,
    const float* __restrict__ lwbuf, const float* __restrict__ flnw,
    const float* __restrict__ alphap, u16* __restrict__ y) {
  __shared__ float red[4];
  const int row = blockIdx.x, tid = threadIdx.x;  // row = b*1024+t
  float a[4] = {0.f, 0.f, 0.f, 0.f};
  const int nsl[3] = {1, 2, 3};
  const int sl[3][3] = {{5, 0, 0}, {0, 4, 0}, {1, 2, 3}};
#pragma unroll
  for (int l = 0; l < 3; l++) {
    float o0 = 0.f, o1 = 0.f, o2 = 0.f, o3 = 0.f, ls = 0.f;
#pragma unroll
    for (int si = 0; si < 3; si++) {
      if (si >= nsl[l]) break;
      int z = sl[l][si];
      float4 v = ((const float4*)(obS + ((size_t)z * 2048 + row) * 1024))[tid];
      o0 += v.x; o1 += v.y; o2 += v.z; o3 += v.w;
      ls += lbufp[((size_t)z * 2048 + row) * 16 + (tid >> 4)];
    }
    float linv = 1.f / ls;
    float v0 = o0 * linv, v1 = o1 * linv, v2 = o2 * linv, v3 = o3 * linv;
    float ss = v0 * v0 + v1 * v1 + v2 * v2 + v3 * v3;
    ss = block_sum(ss, red);
    float rstd = rsqrtf(ss * (1.f / 1024.f) + 1e-5f);
    float lw = lwbuf[l];
    float4 w = ((const float4*)(lnw + (size_t)l * 1024))[tid];
    a[0] += v0 * rstd * w.x * lw;
    a[1] += v1 * rstd * w.y * lw;
    a[2] += v2 * rstd * w.z * lw;
    a[3] += v3 * rstd * w.w * lw;
  }
  const float aa = alphap[0];
  float4 xv = ((const float4*)(x + (size_t)row * 1024))[tid];
  float v0 = a[0] + aa * xv.x, v1 = a[1] + aa * xv.y;
  float v2 = a[2] + aa * xv.z, v3 = a[3] + aa * xv.w;
  float ss = v0 * v0 + v1 * v1 + v2 * v2 + v3 * v3;
  ss = block_sum(ss, red);
  float rstd = rsqrtf(ss * (1.f / 1024.f) + 1e-5f);
  float4 fw = ((const float4*)flnw)[tid];
  ushort4 o;
  o.x = f2bf(v0 * rstd * fw.x); o.y = f2bf(v1 * rstd * fw.y);
  o.z = f2bf(v2 * rstd * fw.z); o.w = f2bf(v3 * rstd * fw.w);
  ((ushort4*)(y + (size_t)row * 1024))[tid] = o;
}

extern "C" void kernel_launch(void* const* d_in, const int* in_sizes, int n_in,
                              void* d_out, int out_size, void* d_ws, size_t ws_size,
                              hipStream_t stream) {
  const float* x     = (const float*)d_in[0];
  const float* cosb  = (const float*)d_in[1];
  const float* sinb  = (const float*)d_in[2];
  const float* qw    = (const float*)d_in[3];
  const float* kw    = (const float*)d_in[4];
  const float* vw    = (const float*)d_in[5];
  const float* lnw   = (const float*)d_in[6];
  const float* lam   = (const float*)d_in[7];
  const float* outw  = (const float*)d_in[8];
  const float* flnw  = (const float*)d_in[9];
  const float* alphap= (const float*)d_in[10];
  float* out = (float*)d_out;
  char* ws = (char*)d_ws;
  // workspace (~82.6 MB). Region [0,48MB) is time-shared:
  //   phase 1: xb [0,4M) + wcat [4M,16M) + qkvb [16M,40M)
  //   phase 2: obS [0,48M)  [z][b][t][h*64+d] fp32 slots
  u16*   xb    = (u16*)  (ws + 0);          //  4 MB
  u16*   wcat  = (u16*)  (ws + 4194304);    // 12 MB
  u16*   qkvb  = (u16*)  (ws + 16777216);   // 24 MB
  float* obS   = (float*)(ws + 0);          // 48 MB
  u16*   outwb = (u16*)  (ws + 50331648);   //  2 MB
  float* lwbuf = (float*)(ws + 52428800);   //  1 KB
  u16*   qr    = (u16*)  (ws + 52429824);   // 12 MB  [3][2][16][1024][64]
  u16*   kr    = (u16*)  (ws + 65012736);   //  6 MB  [2][8][3072][64]
  u16*   vt    = (u16*)  (ws + 71304192);   //  6 MB  [2][8][64][3072]
  float* lbufp = (float*)(ws + 77595648);   // 768 KB [6][2048][16]
  u16*   yb    = (u16*)  (ws + 78382080);   //  4 MB

  prep_kernel<<<9216, 256, 0, stream>>>(x, qw, kw, vw, outw, lam, xb, wcat, outwb, lwbuf);
  gemm128<<<dim3(16, 48), 256, 0, stream>>>(xb, wcat, qkvb, 6144, 1024, 1);
  reshape_kernel<<<3072, 256, 0, stream>>>(qkvb, cosb, sinb, qr, kr, vt);
  attn_v3<<<dim3(8, 32, 6), 256, 0, stream>>>(qr, kr, vt, obS, lbufp);
  fused_norm<<<2048, 256, 0, stream>>>(obS, lbufp, x, lnw, lwbuf, flnw, alphap, yb);
  gemm_bt<<<dim3(32, 16), 256, 0, stream>>>(yb, outwb, out, 1024, 1024);
}

// Round 6
// 285.364 us; speedup vs baseline: 1.3470x; 1.3470x over previous
//
#include <hip/hip_runtime.h>
#include <type_traits>
#include <utility>

typedef unsigned short u16;
typedef unsigned int u32;
typedef short short8 __attribute__((ext_vector_type(8)));
typedef __bf16 bf16x8 __attribute__((ext_vector_type(8)));
typedef float floatx4 __attribute__((ext_vector_type(4)));

// ---- MFMA wrapper robust to either builtin signature (short8 vs v8bf16) ----
template <typename V, typename = void> struct MfmaTakes : std::false_type {};
template <typename V>
struct MfmaTakes<V, std::void_t<decltype(__builtin_amdgcn_mfma_f32_16x16x32_bf16(
    std::declval<V>(), std::declval<V>(), std::declval<floatx4>(), 0, 0, 0))>>
    : std::true_type {};

template <typename V>
__device__ __forceinline__ floatx4 mfma_impl(V a, V b, floatx4 c, std::true_type) {
  return __builtin_amdgcn_mfma_f32_16x16x32_bf16(a, b, c, 0, 0, 0);
}
template <typename V>
__device__ __forceinline__ floatx4 mfma_impl(V a, V b, floatx4 c, std::false_type) {
  return __builtin_amdgcn_mfma_f32_16x16x32_bf16(
      __builtin_bit_cast(bf16x8, a), __builtin_bit_cast(bf16x8, b), c, 0, 0, 0);
}
__device__ __forceinline__ floatx4 MFMA16(short8 a, short8 b, floatx4 c) {
  return mfma_impl<short8>(a, b, c, MfmaTakes<short8>{});
}

__device__ __forceinline__ u16 f2bf(float f) {
  union { float f; unsigned u; } x; x.f = f;
  unsigned r = (x.u + 0x7fffu + ((x.u >> 16) & 1u)) >> 16;
  return (u16)r;
}
__device__ __forceinline__ float bf2f(u16 v) {
  union { unsigned u; float f; } x; x.u = ((unsigned)v) << 16; return x.f;
}
__device__ __forceinline__ u32 packbf(float lo, float hi) {
  return (__float_as_uint(hi) & 0xffff0000u) | (__float_as_uint(lo) >> 16);
}

// ---- async global->LDS staging (16B/lane), fallback to vector copy ----
#if defined(__has_builtin)
#if __has_builtin(__builtin_amdgcn_global_load_lds)
#define HAS_GLLDS 1
#endif
#endif
__device__ __forceinline__ void stage16(const u16* g, u16* lbase, int lane) {
#ifdef HAS_GLLDS
  __builtin_amdgcn_global_load_lds(
      (__attribute__((address_space(1))) void*)(g),
      (__attribute__((address_space(3))) void*)(lbase), 16, 0, 0);
#else
  *(uint4*)(lbase + lane * 8) = *(const uint4*)g;
#endif
}

// ---------------- prep: x->bf16, concat W->bf16, out_w->bf16, lambda weights
__global__ __launch_bounds__(256) void prep_kernel(
    const float* __restrict__ x, const float* __restrict__ qw,
    const float* __restrict__ kw, const float* __restrict__ vw,
    const float* __restrict__ outw, const float* __restrict__ lam,
    u16* __restrict__ xb, u16* __restrict__ wcat, u16* __restrict__ outwb,
    float* __restrict__ lwbuf) {
  size_t gid = (size_t)blockIdx.x * 256 + threadIdx.x;
  if (gid == 0) {
    float s0 = 1.f / (1.f + expf(-lam[0]));
    float s1 = 1.f / (1.f + expf(-lam[1]));
    float s2 = 1.f / (1.f + expf(-lam[2]));
    float mean = (s0 + s1 + s2) * (1.f / 3.f);
    float d0 = s0 - mean, d1 = s1 - mean, d2 = s2 - mean;
    float var = (d0 * d0 + d1 * d1 + d2 * d2) * (1.f / 3.f);
    float r = rsqrtf(var + 1e-5f);
    lwbuf[0] = d0 * r; lwbuf[1] = d1 * r; lwbuf[2] = d2 * r;
  }
  if (gid < 524288) {
    float4 v = ((const float4*)x)[gid];
    ushort4 o; o.x = f2bf(v.x); o.y = f2bf(v.y); o.z = f2bf(v.z); o.w = f2bf(v.w);
    ((ushort4*)xb)[gid] = o;
    return;
  }
  size_t g2 = gid - 524288;
  if (g2 < 1572864) {  // wcat rows: [layer][q(1024)|k(512)|v(512)] x 1024 cols
    int col4 = (int)(g2 & 255);
    int n = (int)(g2 >> 8);
    int layer = n >> 11, r = n & 2047;
    const float* srcrow;
    if (r < 1024) srcrow = qw + ((size_t)(layer * 1024 + r) << 10);
    else if (r < 1536) srcrow = kw + ((size_t)(layer * 512 + (r - 1024)) << 10);
    else srcrow = vw + ((size_t)(layer * 512 + (r - 1536)) << 10);
    float4 v = ((const float4*)srcrow)[col4];
    ushort4 o; o.x = f2bf(v.x); o.y = f2bf(v.y); o.z = f2bf(v.z); o.w = f2bf(v.w);
    ((ushort4*)wcat)[g2] = o;
    return;
  }
  size_t g3 = g2 - 1572864;
  if (g3 < 262144) {
    float4 v = ((const float4*)outw)[g3];
    ushort4 o; o.x = f2bf(v.x); o.y = f2bf(v.y); o.z = f2bf(v.z); o.w = f2bf(v.w);
    ((ushort4*)outwb)[g3] = o;
  }
}

// ---------------- GEMM 128x128 tile, global_load_lds staging, XCD-swizzled 1D grid
__global__ __launch_bounds__(256) void gemm128(
    const u16* __restrict__ A, const u16* __restrict__ Bw,
    void* __restrict__ Cp, int N, int K, int obf16) {
  __shared__ u16 As[128][64];
  __shared__ u16 Bs[128][64];
  // flat = (bn%8) + 8*bm + 128*(bn/8): same bn -> same XCD (L2 reuse of B tile)
  const unsigned flat = blockIdx.x;
  const int bm = (flat >> 3) & 15;
  const int bn = ((flat >> 7) << 3) + (flat & 7);
  const int tid = threadIdx.x;
  const int wave = tid >> 6, lane = tid & 63;
  const int quad = lane >> 4, l16 = lane & 15;
  const int wm = wave & 1, wn = wave >> 1;
  const int srow = lane >> 3, skc = (lane & 7) * 8;
  floatx4 acc[4][4];
#pragma unroll
  for (int i = 0; i < 4; i++)
#pragma unroll
    for (int j = 0; j < 4; j++) { acc[i][j][0] = 0.f; acc[i][j][1] = 0.f; acc[i][j][2] = 0.f; acc[i][j][3] = 0.f; }
  const u16* Abase = A + (size_t)(bm * 128) * K;
  const u16* Bbase = Bw + (size_t)(bn * 128) * K;
  for (int k0 = 0; k0 < K; k0 += 64) {
    __syncthreads();
#pragma unroll
    for (int i = 0; i < 4; i++) {
      int ch = wave * 4 + i;
      stage16(Abase + (size_t)(ch * 8 + srow) * K + k0 + skc, &As[ch * 8][0], lane);
      stage16(Bbase + (size_t)(ch * 8 + srow) * K + k0 + skc, &Bs[ch * 8][0], lane);
    }
    __syncthreads();
#pragma unroll
    for (int kf = 0; kf < 2; kf++) {
      short8 af[4], bf[4];
#pragma unroll
      for (int mi = 0; mi < 4; mi++)
        af[mi] = *(const short8*)(&As[wm * 64 + mi * 16 + l16][kf * 32 + quad * 8]);
#pragma unroll
      for (int ni = 0; ni < 4; ni++)
        bf[ni] = *(const short8*)(&Bs[wn * 64 + ni * 16 + l16][kf * 32 + quad * 8]);
#pragma unroll
      for (int mi = 0; mi < 4; mi++)
#pragma unroll
        for (int ni = 0; ni < 4; ni++)
          acc[mi][ni] = MFMA16(af[mi], bf[ni], acc[mi][ni]);
    }
  }
  float* Cf = (float*)Cp;
  u16* Cb = (u16*)Cp;
#pragma unroll
  for (int mi = 0; mi < 4; mi++)
#pragma unroll
    for (int ni = 0; ni < 4; ni++)
#pragma unroll
      for (int r = 0; r < 4; r++) {
        int row = bm * 128 + wm * 64 + mi * 16 + quad * 4 + r;
        int col = bn * 128 + wn * 64 + ni * 16 + l16;
        if (obf16) Cb[(size_t)row * N + col] = f2bf(acc[mi][ni][r]);
        else Cf[(size_t)row * N + col] = acc[mi][ni][r];
      }
}

// ---------------- small GEMM (64x64 tile) for the out-projection
__global__ __launch_bounds__(256) void gemm_bt(
    const u16* __restrict__ A, const u16* __restrict__ Bw,
    float* __restrict__ C, int N, int K) {
  __shared__ u16 As[64][72];
  __shared__ u16 Bs[64][72];
  const int bm = blockIdx.x, bn = blockIdx.y;
  const int tid = threadIdx.x;
  const int wave = tid >> 6, lane = tid & 63;
  const int quad = lane >> 4, l16 = lane & 15;
  const int lr = tid >> 2, lc = (tid & 3) << 4;
  floatx4 acc[4];
#pragma unroll
  for (int i = 0; i < 4; i++) { acc[i][0] = 0.f; acc[i][1] = 0.f; acc[i][2] = 0.f; acc[i][3] = 0.f; }
  const u16* Arow = A + (size_t)(bm * 64 + lr) * K;
  const u16* Brow = Bw + (size_t)(bn * 64 + lr) * K;
  for (int k0 = 0; k0 < K; k0 += 64) {
    __syncthreads();
    *(uint4*)(&As[lr][lc])     = *(const uint4*)(Arow + k0 + lc);
    *(uint4*)(&As[lr][lc + 8]) = *(const uint4*)(Arow + k0 + lc + 8);
    *(uint4*)(&Bs[lr][lc])     = *(const uint4*)(Brow + k0 + lc);
    *(uint4*)(&Bs[lr][lc + 8]) = *(const uint4*)(Brow + k0 + lc + 8);
    __syncthreads();
    const int mrow = wave * 16 + l16;
    short8 a0 = *(const short8*)(&As[mrow][quad * 8]);
    short8 a1 = *(const short8*)(&As[mrow][32 + quad * 8]);
#pragma unroll
    for (int ns = 0; ns < 4; ns++) {
      short8 b0 = *(const short8*)(&Bs[ns * 16 + l16][quad * 8]);
      short8 b1 = *(const short8*)(&Bs[ns * 16 + l16][32 + quad * 8]);
      acc[ns] = MFMA16(a0, b0, acc[ns]);
      acc[ns] = MFMA16(a1, b1, acc[ns]);
    }
  }
#pragma unroll
  for (int ns = 0; ns < 4; ns++)
#pragma unroll
    for (int r = 0; r < 4; r++) {
      int row = bm * 64 + wave * 16 + quad * 4 + r;
      int col = bn * 64 + ns * 16 + l16;
      C[(size_t)row * N + col] = acc[ns][r];
    }
}

// ---------------- fused reshape: RoPE Q (x0.125) + RoPE K + V transpose
__global__ __launch_bounds__(256) void reshape_kernel(
    const u16* __restrict__ qkvb, const float* __restrict__ cosb,
    const float* __restrict__ sinb, u16* __restrict__ qr,
    u16* __restrict__ kr, u16* __restrict__ vtg) {
  __shared__ u16 T[64][72];
  const int bid = blockIdx.x, tid = threadIdx.x;
  union U8 { uint4 v; u16 s[8]; };
  union F8 { float4 v[2]; float f[8]; };
  if (bid < 2304) {
    unsigned gid = (unsigned)bid * 256 + tid;
    if (gid < 393216u) {  // Q
      int d8 = gid & 3, t = (gid >> 2) & 1023, h = (gid >> 12) & 15;
      int b = (gid >> 16) & 1, layer = gid >> 17;
      size_t src = (size_t)(b * 1024 + t) * 6144 + layer * 2048 + h * 64 + d8 * 8;
      U8 xa, xc; xa.v = *(const uint4*)(qkvb + src); xc.v = *(const uint4*)(qkvb + src + 32);
      F8 C, S;
      const float4* cp = (const float4*)(cosb + (size_t)t * 32 + d8 * 8);
      const float4* sp = (const float4*)(sinb + (size_t)t * 32 + d8 * 8);
      C.v[0] = cp[0]; C.v[1] = cp[1]; S.v[0] = sp[0]; S.v[1] = sp[1];
      U8 o1, o2;
#pragma unroll
      for (int j = 0; j < 8; j++) {
        float x1 = bf2f(xa.s[j]), x2 = bf2f(xc.s[j]);
        o1.s[j] = f2bf((x1 * C.f[j] - x2 * S.f[j]) * 0.125f);  // fold HD^-0.5
        o2.s[j] = f2bf((x2 * C.f[j] + x1 * S.f[j]) * 0.125f);
      }
      size_t dst = ((((size_t)layer * 2 + b) * 16 + h) * 1024 + t) * 64 + d8 * 8;
      *(uint4*)(qr + dst) = o1.v;
      *(uint4*)(qr + dst + 32) = o2.v;
      return;
    }
    unsigned g2 = gid - 393216u;
    if (g2 < 196608u) {  // K
      int d8 = g2 & 3, t = (g2 >> 2) & 1023, h = (g2 >> 12) & 7;
      int b = (g2 >> 15) & 1, layer = g2 >> 16;
      int pos = layer * 1024 + t;  // layer-j keys sit at offset j*T
      size_t src = (size_t)(b * 1024 + t) * 6144 + layer * 2048 + 1024 + h * 64 + d8 * 8;
      U8 xa, xc; xa.v = *(const uint4*)(qkvb + src); xc.v = *(const uint4*)(qkvb + src + 32);
      F8 C, S;
      const float4* cp = (const float4*)(cosb + (size_t)pos * 32 + d8 * 8);
      const float4* sp = (const float4*)(sinb + (size_t)pos * 32 + d8 * 8);
      C.v[0] = cp[0]; C.v[1] = cp[1]; S.v[0] = sp[0]; S.v[1] = sp[1];
      U8 o1, o2;
#pragma unroll
      for (int j = 0; j < 8; j++) {
        float x1 = bf2f(xa.s[j]), x2 = bf2f(xc.s[j]);
        o1.s[j] = f2bf(x1 * C.f[j] - x2 * S.f[j]);
        o2.s[j] = f2bf(x2 * C.f[j] + x1 * S.f[j]);
      }
      size_t dst = (((size_t)b * 8 + h) * 3072 + pos) * 64 + d8 * 8;
      *(uint4*)(kr + dst) = o1.v;
      *(uint4*)(kr + dst + 32) = o2.v;
    }
    return;
  }
  // V transpose -> vt [B][HKV][64][3072]
  const int b2 = bid - 2304;
  const int xt = b2 & 15;
  const int y = b2 >> 4;
  const int layer = y >> 4, b = (y >> 3) & 1, h = y & 7;
  const int t0 = xt * 64;
  {
    const int p = tid >> 2, dc = (tid & 3) * 16;
    const u16* src = qkvb + (size_t)(b * 1024 + t0 + p) * 6144 + layer * 2048 + 1536 + h * 64 + dc;
    U8 u0, u1;
    u0.v = *(const uint4*)(src);
    u1.v = *(const uint4*)(src + 8);
#pragma unroll
    for (int j = 0; j < 8; j++) { T[dc + j][p] = u0.s[j]; T[dc + 8 + j][p] = u1.s[j]; }
  }
  __syncthreads();
  {
    const int d = tid >> 2, pc = (tid & 3) * 16;
    u16* dst = vtg + ((size_t)((b * 8 + h) * 64 + d)) * 3072 + layer * 1024 + t0 + pc;
    *(uint4*)(dst) = *(const uint4*)(&T[d][pc]);
    *(uint4*)(dst + 8) = *(const uint4*)(&T[d][pc + 8]);
  }
}

// ---------------- attention v4: r4 LDS-staged S^T structure
//  + XCD-swizzled 1D grid (same head/chunk pinned to one XCD -> L2 KV reuse)
//  + register prefetch of next K/V tile (global latency off the barrier path)
//  + LDS stride 70 (odd word count -> ~2-way max bank aliasing)
//  + r5 row-major epilogue (obS slots, coalesced fused_norm)
__global__ __launch_bounds__(256) void attn_v4(
    const u16* __restrict__ qr, const u16* __restrict__ kr,
    const u16* __restrict__ vt, float* __restrict__ obS,
    float* __restrict__ lbufp) {
  __shared__ u16 Kt[64][70];        // [key][d]
  __shared__ u16 Vt[64][70];        // [d][key]
  __shared__ u16 Pw[4][2][16][70];  // [wave][nt][q][key]; fp32 scratch in epilogue
  // flat = (bhz%8) + 8*qtile' + 64*(bhz/8); bhz = z*32+bh
  const unsigned flat = blockIdx.x;
  const int bhz = (int)((flat >> 6) * 8 + (flat & 7));
  const int qtile = 7 - (int)((flat >> 3) & 7);   // heavy partials first
  const int z = bhz >> 5;
  const int bh = bhz & 31;
  const int lay = (0x012221u >> (z * 4)) & 0xF;  // z: (1,0)(2,0)(2,1)(2,2)(1,1)(0,0)
  const int c   = (0x012100u >> (z * 4)) & 0xF;
  const int b = bh >> 4, h = bh & 15, hk = h >> 1;
  const int tid = threadIdx.x, wave = tid >> 6, lane = tid & 63;
  const int quad = lane >> 4, l16 = lane & 15;
  const int kt0 = c * 16;
  const int kt1 = (c == lay) ? (lay * 16 + 2 * qtile + 2) : (kt0 + 16);
  const int maskkt = lay * 16 + 2 * qtile;
  const int qeffbase = lay * 1024 + qtile * 128 + wave * 32;
  const u16* qpb = qr + ((((size_t)lay * 2 + b) * 16 + h) * 1024
                         + qtile * 128 + wave * 32 + l16) * 64 + quad * 8;
  short8 qf[2][2];
  qf[0][0] = *(const short8*)(qpb);
  qf[0][1] = *(const short8*)(qpb + 32);
  qf[1][0] = *(const short8*)(qpb + 1024);
  qf[1][1] = *(const short8*)(qpb + 1056);
  const short8 ones = {16256, 16256, 16256, 16256, 16256, 16256, 16256, 16256};
  floatx4 oacc[2][4];
#pragma unroll
  for (int nt = 0; nt < 2; nt++)
#pragma unroll
    for (int dt = 0; dt < 4; dt++) { oacc[nt][dt][0] = 0.f; oacc[nt][dt][1] = 0.f; oacc[nt][dt][2] = 0.f; oacc[nt][dt][3] = 0.f; }
  floatx4 lacc[2];
  lacc[0][0] = 0.f; lacc[0][1] = 0.f; lacc[0][2] = 0.f; lacc[0][3] = 0.f;
  lacc[1] = lacc[0];
  const int sr = tid >> 2, sc = (tid & 3) << 4;
  const u16* kp = kr + ((size_t)(b * 8 + hk) * 3072 + kt0 * 64 + sr) * 64 + sc;
  const u16* vp = vt + ((size_t)(b * 8 + hk) * 64 + sr) * 3072 + kt0 * 64 + sc;
  // prime the register prefetch with tile kt0
  uint4 kA = *(const uint4*)(kp), kB = *(const uint4*)(kp + 8);
  uint4 vA = *(const uint4*)(vp), vB = *(const uint4*)(vp + 8);
  for (int kt = kt0; kt < kt1; kt++) {
    kp += 4096; vp += 64;  // -> next tile
    __syncthreads();
    *(uint4*)(&Kt[sr][sc])     = kA;
    *(uint4*)(&Kt[sr][sc + 8]) = kB;
    *(uint4*)(&Vt[sr][sc])     = vA;
    *(uint4*)(&Vt[sr][sc + 8]) = vB;
    if (kt + 1 < kt1) {  // prefetch next tile during this tile's compute
      kA = *(const uint4*)(kp); kB = *(const uint4*)(kp + 8);
      vA = *(const uint4*)(vp); vB = *(const uint4*)(vp + 8);
    }
    __syncthreads();
    const bool needmask = (kt >= maskkt);
    // S^T = K Q^T : per mt (16 keys), both n-tiles share the K fragment
#pragma unroll
    for (int mt = 0; mt < 4; mt++) {
      short8 kfa = *(const short8*)(&Kt[mt * 16 + l16][quad * 8]);
      short8 kfb = *(const short8*)(&Kt[mt * 16 + l16][32 + quad * 8]);
      const int keyb = kt * 64 + mt * 16 + quad * 4;
#pragma unroll
      for (int nt = 0; nt < 2; nt++) {
        floatx4 s; s[0] = 0.f; s[1] = 0.f; s[2] = 0.f; s[3] = 0.f;
        s = MFMA16(kfa, qf[nt][0], s);
        s = MFMA16(kfb, qf[nt][1], s);
        float p0 = __expf(s[0]), p1 = __expf(s[1]);
        float p2 = __expf(s[2]), p3 = __expf(s[3]);
        if (needmask) {
          int qpos = qeffbase + nt * 16 + l16;
          if (keyb + 0 > qpos) p0 = 0.f;
          if (keyb + 1 > qpos) p1 = 0.f;
          if (keyb + 2 > qpos) p2 = 0.f;
          if (keyb + 3 > qpos) p3 = 0.f;
        }
        uint2 st; st.x = packbf(p0, p1); st.y = packbf(p2, p3);
        *(uint2*)(&Pw[wave][nt][l16][mt * 16 + quad * 4]) = st;
      }
    }
    // O^T += V^T P ; l += col-sums (per-wave LDS region: no barrier)
#pragma unroll
    for (int kc = 0; kc < 2; kc++) {
      short8 pf0 = *(const short8*)(&Pw[wave][0][l16][kc * 32 + quad * 8]);
      short8 pf1 = *(const short8*)(&Pw[wave][1][l16][kc * 32 + quad * 8]);
      lacc[0] = MFMA16(ones, pf0, lacc[0]);
      lacc[1] = MFMA16(ones, pf1, lacc[1]);
#pragma unroll
      for (int dt = 0; dt < 4; dt++) {
        short8 vf = *(const short8*)(&Vt[dt * 16 + l16][kc * 32 + quad * 8]);
        oacc[0][dt] = MFMA16(vf, pf0, oacc[0][dt]);
        oacc[1][dt] = MFMA16(vf, pf1, oacc[1][dt]);
      }
    }
  }
  // epilogue: O^T (d=row, t=col) -> row-major [t][d] via per-wave LDS tile
  float* Pf = (float*)(&Pw[wave][0][0][0]);  // 4480 B/wave >= 2*16*20*4
  const int tt = lane >> 2, dd = (lane & 3) << 2;
#pragma unroll
  for (int nt = 0; nt < 2; nt++) {
    int t = qtile * 128 + wave * 32 + nt * 16 + l16;
    if (quad == 0)
      lbufp[((size_t)z * 2048 + b * 1024 + t) * 16 + h] = lacc[nt][0];
    int t2 = qtile * 128 + wave * 32 + nt * 16 + tt;
    float* orow = obS + ((size_t)(z * 2 + b) * 1024 + t2) * 1024 + h * 64 + dd;
#pragma unroll
    for (int dt = 0; dt < 4; dt++) {
      *(floatx4*)(&Pf[nt * 320 + l16 * 20 + quad * 4]) = oacc[nt][dt];  // [t][d] tile
      floatx4 val = *(const floatx4*)(&Pf[nt * 320 + tt * 20 + dd]);    // wave in-order
      *(floatx4*)(orow + dt * 16) = val;
    }
  }
}

// ---------------- fused: slot-sum (coalesced rows), /l, rmsnorm chain
__device__ __forceinline__ float block_sum(float v, float* red) {
  v += __shfl_xor(v, 32); v += __shfl_xor(v, 16); v += __shfl_xor(v, 8);
  v += __shfl_xor(v, 4);  v += __shfl_xor(v, 2);  v += __shfl_xor(v, 1);
  __syncthreads();
  if ((threadIdx.x & 63) == 0) red[threadIdx.x >> 6] = v;
  __syncthreads();
  return red[0] + red[1] + red[2] + red[3];
}

__global__ __launch_bounds__(256) void fused_norm(
    const float* __restrict__ obS, const float* __restrict__ lbufp,
    const float* __restrict__ x, const float* __restrict__ lnw,
    const float* __restrict__ lwbuf, const float* __restrict__ flnw,
    const float* __restrict__ alphap, u16* __restrict__ y) {
  __shared__ float red[4];
  const int row = blockIdx.x, tid = threadIdx.x;  // row = b*1024+t
  float a[4] = {0.f, 0.f, 0.f, 0.f};
  const int nsl[3] = {1, 2, 3};
  const int sl[3][3] = {{5, 0, 0}, {0, 4, 0}, {1, 2, 3}};
#pragma unroll
  for (int l = 0; l < 3; l++) {
    float o0 = 0.f, o1 = 0.f, o2 = 0.f, o3 = 0.f, ls = 0.f;
#pragma unroll
    for (int si = 0; si < 3; si++) {
      if (si >= nsl[l]) break;
      int z = sl[l][si];
      float4 v = ((const float4*)(obS + ((size_t)z * 2048 + row) * 1024))[tid];
      o0 += v.x; o1 += v.y; o2 += v.z; o3 += v.w;
      ls += lbufp[((size_t)z * 2048 + row) * 16 + (tid >> 4)];
    }
    float linv = 1.f / ls;
    float v0 = o0 * linv, v1 = o1 * linv, v2 = o2 * linv, v3 = o3 * linv;
    float ss = v0 * v0 + v1 * v1 + v2 * v2 + v3 * v3;
    ss = block_sum(ss, red);
    float rstd = rsqrtf(ss * (1.f / 1024.f) + 1e-5f);
    float lw = lwbuf[l];
    float4 w = ((const float4*)(lnw + (size_t)l * 1024))[tid];
    a[0] += v0 * rstd * w.x * lw;
    a[1] += v1 * rstd * w.y * lw;
    a[2] += v2 * rstd * w.z * lw;
    a[3] += v3 * rstd * w.w * lw;
  }
  const float aa = alphap[0];
  float4 xv = ((const float4*)(x + (size_t)row * 1024))[tid];
  float v0 = a[0] + aa * xv.x, v1 = a[1] + aa * xv.y;
  float v2 = a[2] + aa * xv.z, v3 = a[3] + aa * xv.w;
  float ss = v0 * v0 + v1 * v1 + v2 * v2 + v3 * v3;
  ss = block_sum(ss, red);
  float rstd = rsqrtf(ss * (1.f / 1024.f) + 1e-5f);
  float4 fw = ((const float4*)flnw)[tid];
  ushort4 o;
  o.x = f2bf(v0 * rstd * fw.x); o.y = f2bf(v1 * rstd * fw.y);
  o.z = f2bf(v2 * rstd * fw.z); o.w = f2bf(v3 * rstd * fw.w);
  ((ushort4*)(y + (size_t)row * 1024))[tid] = o;
}

extern "C" void kernel_launch(void* const* d_in, const int* in_sizes, int n_in,
                              void* d_out, int out_size, void* d_ws, size_t ws_size,
                              hipStream_t stream) {
  const float* x     = (const float*)d_in[0];
  const float* cosb  = (const float*)d_in[1];
  const float* sinb  = (const float*)d_in[2];
  const float* qw    = (const float*)d_in[3];
  const float* kw    = (const float*)d_in[4];
  const float* vw    = (const float*)d_in[5];
  const float* lnw   = (const float*)d_in[6];
  const float* lam   = (const float*)d_in[7];
  const float* outw  = (const float*)d_in[8];
  const float* flnw  = (const float*)d_in[9];
  const float* alphap= (const float*)d_in[10];
  float* out = (float*)d_out;
  char* ws = (char*)d_ws;
  // workspace (~82.6 MB). Region [0,48MB) is time-shared:
  //   phase 1: xb [0,4M) + wcat [4M,16M) + qkvb [16M,40M)
  //   phase 2: obS [0,48M)  [z][b][t][h*64+d] fp32 slots
  u16*   xb    = (u16*)  (ws + 0);          //  4 MB
  u16*   wcat  = (u16*)  (ws + 4194304);    // 12 MB
  u16*   qkvb  = (u16*)  (ws + 16777216);   // 24 MB
  float* obS   = (float*)(ws + 0);          // 48 MB
  u16*   outwb = (u16*)  (ws + 50331648);   //  2 MB
  float* lwbuf = (float*)(ws + 52428800);   //  1 KB
  u16*   qr    = (u16*)  (ws + 52429824);   // 12 MB  [3][2][16][1024][64]
  u16*   kr    = (u16*)  (ws + 65012736);   //  6 MB  [2][8][3072][64]
  u16*   vt    = (u16*)  (ws + 71304192);   //  6 MB  [2][8][64][3072]
  float* lbufp = (float*)(ws + 77595648);   // 768 KB [6][2048][16]
  u16*   yb    = (u16*)  (ws + 78382080);   //  4 MB

  prep_kernel<<<9216, 256, 0, stream>>>(x, qw, kw, vw, outw, lam, xb, wcat, outwb, lwbuf);
  gemm128<<<768, 256, 0, stream>>>(xb, wcat, qkvb, 6144, 1024, 1);
  reshape_kernel<<<3072, 256, 0, stream>>>(qkvb, cosb, sinb, qr, kr, vt);
  attn_v4<<<1536, 256, 0, stream>>>(qr, kr, vt, obS, lbufp);
  fused_norm<<<2048, 256, 0, stream>>>(obS, lbufp, x, lnw, lwbuf, flnw, alphap, yb);
  gemm_bt<<<dim3(32, 16), 256, 0, stream>>>(yb, outwb, out, 1024, 1024);
}

// Round 7
// 262.497 us; speedup vs baseline: 1.4643x; 1.0871x over previous
//
#include <hip/hip_runtime.h>
#include <type_traits>
#include <utility>

typedef unsigned short u16;
typedef unsigned int u32;
typedef short short8 __attribute__((ext_vector_type(8)));
typedef __bf16 bf16x8 __attribute__((ext_vector_type(8)));
typedef float floatx4 __attribute__((ext_vector_type(4)));

// ---- MFMA wrapper robust to either builtin signature (short8 vs v8bf16) ----
template <typename V, typename = void> struct MfmaTakes : std::false_type {};
template <typename V>
struct MfmaTakes<V, std::void_t<decltype(__builtin_amdgcn_mfma_f32_16x16x32_bf16(
    std::declval<V>(), std::declval<V>(), std::declval<floatx4>(), 0, 0, 0))>>
    : std::true_type {};

template <typename V>
__device__ __forceinline__ floatx4 mfma_impl(V a, V b, floatx4 c, std::true_type) {
  return __builtin_amdgcn_mfma_f32_16x16x32_bf16(a, b, c, 0, 0, 0);
}
template <typename V>
__device__ __forceinline__ floatx4 mfma_impl(V a, V b, floatx4 c, std::false_type) {
  return __builtin_amdgcn_mfma_f32_16x16x32_bf16(
      __builtin_bit_cast(bf16x8, a), __builtin_bit_cast(bf16x8, b), c, 0, 0, 0);
}
__device__ __forceinline__ floatx4 MFMA16(short8 a, short8 b, floatx4 c) {
  return mfma_impl<short8>(a, b, c, MfmaTakes<short8>{});
}

__device__ __forceinline__ u16 f2bf(float f) {
  union { float f; unsigned u; } x; x.f = f;
  unsigned r = (x.u + 0x7fffu + ((x.u >> 16) & 1u)) >> 16;
  return (u16)r;
}
__device__ __forceinline__ float bf2f(u16 v) {
  union { unsigned u; float f; } x; x.u = ((unsigned)v) << 16; return x.f;
}
__device__ __forceinline__ u32 packbf(float lo, float hi) {
  return (__float_as_uint(hi) & 0xffff0000u) | (__float_as_uint(lo) >> 16);
}

// ---- async global->LDS staging (16B/lane), fallback to vector copy ----
#if defined(__has_builtin)
#if __has_builtin(__builtin_amdgcn_global_load_lds)
#define HAS_GLLDS 1
#endif
#endif
__device__ __forceinline__ void stage16(const u16* g, u16* lbase, int lane) {
#ifdef HAS_GLLDS
  __builtin_amdgcn_global_load_lds(
      (__attribute__((address_space(1))) void*)(g),
      (__attribute__((address_space(3))) void*)(lbase), 16, 0, 0);
#else
  *(uint4*)(lbase + lane * 8) = *(const uint4*)g;
#endif
}

// ---------------- prep: x->bf16, concat W->bf16, out_w->bf16, lambda weights
__global__ __launch_bounds__(256) void prep_kernel(
    const float* __restrict__ x, const float* __restrict__ qw,
    const float* __restrict__ kw, const float* __restrict__ vw,
    const float* __restrict__ outw, const float* __restrict__ lam,
    u16* __restrict__ xb, u16* __restrict__ wcat, u16* __restrict__ outwb,
    float* __restrict__ lwbuf) {
  size_t gid = (size_t)blockIdx.x * 256 + threadIdx.x;
  if (gid == 0) {
    float s0 = 1.f / (1.f + expf(-lam[0]));
    float s1 = 1.f / (1.f + expf(-lam[1]));
    float s2 = 1.f / (1.f + expf(-lam[2]));
    float mean = (s0 + s1 + s2) * (1.f / 3.f);
    float d0 = s0 - mean, d1 = s1 - mean, d2 = s2 - mean;
    float var = (d0 * d0 + d1 * d1 + d2 * d2) * (1.f / 3.f);
    float r = rsqrtf(var + 1e-5f);
    lwbuf[0] = d0 * r; lwbuf[1] = d1 * r; lwbuf[2] = d2 * r;
  }
  if (gid < 524288) {
    float4 v = ((const float4*)x)[gid];
    ushort4 o; o.x = f2bf(v.x); o.y = f2bf(v.y); o.z = f2bf(v.z); o.w = f2bf(v.w);
    ((ushort4*)xb)[gid] = o;
    return;
  }
  size_t g2 = gid - 524288;
  if (g2 < 1572864) {  // wcat rows: [layer][q(1024)|k(512)|v(512)] x 1024 cols
    int col4 = (int)(g2 & 255);
    int n = (int)(g2 >> 8);
    int layer = n >> 11, r = n & 2047;
    const float* srcrow;
    if (r < 1024) srcrow = qw + ((size_t)(layer * 1024 + r) << 10);
    else if (r < 1536) srcrow = kw + ((size_t)(layer * 512 + (r - 1024)) << 10);
    else srcrow = vw + ((size_t)(layer * 512 + (r - 1536)) << 10);
    float4 v = ((const float4*)srcrow)[col4];
    ushort4 o; o.x = f2bf(v.x); o.y = f2bf(v.y); o.z = f2bf(v.z); o.w = f2bf(v.w);
    ((ushort4*)wcat)[g2] = o;
    return;
  }
  size_t g3 = g2 - 1572864;
  if (g3 < 262144) {
    float4 v = ((const float4*)outw)[g3];
    ushort4 o; o.x = f2bf(v.x); o.y = f2bf(v.y); o.z = f2bf(v.z); o.w = f2bf(v.w);
    ((ushort4*)outwb)[g3] = o;
  }
}

// ---------------- GEMM 128x128 tile, global_load_lds staging, XCD-swizzled 1D grid
__global__ __launch_bounds__(256) void gemm128(
    const u16* __restrict__ A, const u16* __restrict__ Bw,
    void* __restrict__ Cp, int N, int K, int obf16) {
  __shared__ u16 As[128][64];
  __shared__ u16 Bs[128][64];
  const unsigned flat = blockIdx.x;
  const int bm = (flat >> 3) & 15;
  const int bn = ((flat >> 7) << 3) + (flat & 7);
  const int tid = threadIdx.x;
  const int wave = tid >> 6, lane = tid & 63;
  const int quad = lane >> 4, l16 = lane & 15;
  const int wm = wave & 1, wn = wave >> 1;
  const int srow = lane >> 3, skc = (lane & 7) * 8;
  floatx4 acc[4][4];
#pragma unroll
  for (int i = 0; i < 4; i++)
#pragma unroll
    for (int j = 0; j < 4; j++) { acc[i][j][0] = 0.f; acc[i][j][1] = 0.f; acc[i][j][2] = 0.f; acc[i][j][3] = 0.f; }
  const u16* Abase = A + (size_t)(bm * 128) * K;
  const u16* Bbase = Bw + (size_t)(bn * 128) * K;
  for (int k0 = 0; k0 < K; k0 += 64) {
    __syncthreads();
#pragma unroll
    for (int i = 0; i < 4; i++) {
      int ch = wave * 4 + i;
      stage16(Abase + (size_t)(ch * 8 + srow) * K + k0 + skc, &As[ch * 8][0], lane);
      stage16(Bbase + (size_t)(ch * 8 + srow) * K + k0 + skc, &Bs[ch * 8][0], lane);
    }
    __syncthreads();
#pragma unroll
    for (int kf = 0; kf < 2; kf++) {
      short8 af[4], bf[4];
#pragma unroll
      for (int mi = 0; mi < 4; mi++)
        af[mi] = *(const short8*)(&As[wm * 64 + mi * 16 + l16][kf * 32 + quad * 8]);
#pragma unroll
      for (int ni = 0; ni < 4; ni++)
        bf[ni] = *(const short8*)(&Bs[wn * 64 + ni * 16 + l16][kf * 32 + quad * 8]);
#pragma unroll
      for (int mi = 0; mi < 4; mi++)
#pragma unroll
        for (int ni = 0; ni < 4; ni++)
          acc[mi][ni] = MFMA16(af[mi], bf[ni], acc[mi][ni]);
    }
  }
  float* Cf = (float*)Cp;
  u16* Cb = (u16*)Cp;
#pragma unroll
  for (int mi = 0; mi < 4; mi++)
#pragma unroll
    for (int ni = 0; ni < 4; ni++)
#pragma unroll
      for (int r = 0; r < 4; r++) {
        int row = bm * 128 + wm * 64 + mi * 16 + quad * 4 + r;
        int col = bn * 128 + wn * 64 + ni * 16 + l16;
        if (obf16) Cb[(size_t)row * N + col] = f2bf(acc[mi][ni][r]);
        else Cf[(size_t)row * N + col] = acc[mi][ni][r];
      }
}

// ---------------- small GEMM (64x64 tile) for the out-projection
__global__ __launch_bounds__(256) void gemm_bt(
    const u16* __restrict__ A, const u16* __restrict__ Bw,
    float* __restrict__ C, int N, int K) {
  __shared__ u16 As[64][72];
  __shared__ u16 Bs[64][72];
  const int bm = blockIdx.x, bn = blockIdx.y;
  const int tid = threadIdx.x;
  const int wave = tid >> 6, lane = tid & 63;
  const int quad = lane >> 4, l16 = lane & 15;
  const int lr = tid >> 2, lc = (tid & 3) << 4;
  floatx4 acc[4];
#pragma unroll
  for (int i = 0; i < 4; i++) { acc[i][0] = 0.f; acc[i][1] = 0.f; acc[i][2] = 0.f; acc[i][3] = 0.f; }
  const u16* Arow = A + (size_t)(bm * 64 + lr) * K;
  const u16* Brow = Bw + (size_t)(bn * 64 + lr) * K;
  for (int k0 = 0; k0 < K; k0 += 64) {
    __syncthreads();
    *(uint4*)(&As[lr][lc])     = *(const uint4*)(Arow + k0 + lc);
    *(uint4*)(&As[lr][lc + 8]) = *(const uint4*)(Arow + k0 + lc + 8);
    *(uint4*)(&Bs[lr][lc])     = *(const uint4*)(Brow + k0 + lc);
    *(uint4*)(&Bs[lr][lc + 8]) = *(const uint4*)(Brow + k0 + lc + 8);
    __syncthreads();
    const int mrow = wave * 16 + l16;
    short8 a0 = *(const short8*)(&As[mrow][quad * 8]);
    short8 a1 = *(const short8*)(&As[mrow][32 + quad * 8]);
#pragma unroll
    for (int ns = 0; ns < 4; ns++) {
      short8 b0 = *(const short8*)(&Bs[ns * 16 + l16][quad * 8]);
      short8 b1 = *(const short8*)(&Bs[ns * 16 + l16][32 + quad * 8]);
      acc[ns] = MFMA16(a0, b0, acc[ns]);
      acc[ns] = MFMA16(a1, b1, acc[ns]);
    }
  }
#pragma unroll
  for (int ns = 0; ns < 4; ns++)
#pragma unroll
    for (int r = 0; r < 4; r++) {
      int row = bm * 64 + wave * 16 + quad * 4 + r;
      int col = bn * 64 + ns * 16 + l16;
      C[(size_t)row * N + col] = acc[ns][r];
    }
}

// ---------------- fused reshape: RoPE Q (x0.125) + RoPE K + V transpose
__global__ __launch_bounds__(256) void reshape_kernel(
    const u16* __restrict__ qkvb, const float* __restrict__ cosb,
    const float* __restrict__ sinb, u16* __restrict__ qr,
    u16* __restrict__ kr, u16* __restrict__ vtg) {
  __shared__ u16 T[64][72];
  const int bid = blockIdx.x, tid = threadIdx.x;
  union U8 { uint4 v; u16 s[8]; };
  union F8 { float4 v[2]; float f[8]; };
  if (bid < 2304) {
    unsigned gid = (unsigned)bid * 256 + tid;
    if (gid < 393216u) {  // Q
      int d8 = gid & 3, t = (gid >> 2) & 1023, h = (gid >> 12) & 15;
      int b = (gid >> 16) & 1, layer = gid >> 17;
      size_t src = (size_t)(b * 1024 + t) * 6144 + layer * 2048 + h * 64 + d8 * 8;
      U8 xa, xc; xa.v = *(const uint4*)(qkvb + src); xc.v = *(const uint4*)(qkvb + src + 32);
      F8 C, S;
      const float4* cp = (const float4*)(cosb + (size_t)t * 32 + d8 * 8);
      const float4* sp = (const float4*)(sinb + (size_t)t * 32 + d8 * 8);
      C.v[0] = cp[0]; C.v[1] = cp[1]; S.v[0] = sp[0]; S.v[1] = sp[1];
      U8 o1, o2;
#pragma unroll
      for (int j = 0; j < 8; j++) {
        float x1 = bf2f(xa.s[j]), x2 = bf2f(xc.s[j]);
        o1.s[j] = f2bf((x1 * C.f[j] - x2 * S.f[j]) * 0.125f);  // fold HD^-0.5
        o2.s[j] = f2bf((x2 * C.f[j] + x1 * S.f[j]) * 0.125f);
      }
      size_t dst = ((((size_t)layer * 2 + b) * 16 + h) * 1024 + t) * 64 + d8 * 8;
      *(uint4*)(qr + dst) = o1.v;
      *(uint4*)(qr + dst + 32) = o2.v;
      return;
    }
    unsigned g2 = gid - 393216u;
    if (g2 < 196608u) {  // K
      int d8 = g2 & 3, t = (g2 >> 2) & 1023, h = (g2 >> 12) & 7;
      int b = (g2 >> 15) & 1, layer = g2 >> 16;
      int pos = layer * 1024 + t;  // layer-j keys sit at offset j*T
      size_t src = (size_t)(b * 1024 + t) * 6144 + layer * 2048 + 1024 + h * 64 + d8 * 8;
      U8 xa, xc; xa.v = *(const uint4*)(qkvb + src); xc.v = *(const uint4*)(qkvb + src + 32);
      F8 C, S;
      const float4* cp = (const float4*)(cosb + (size_t)pos * 32 + d8 * 8);
      const float4* sp = (const float4*)(sinb + (size_t)pos * 32 + d8 * 8);
      C.v[0] = cp[0]; C.v[1] = cp[1]; S.v[0] = sp[0]; S.v[1] = sp[1];
      U8 o1, o2;
#pragma unroll
      for (int j = 0; j < 8; j++) {
        float x1 = bf2f(xa.s[j]), x2 = bf2f(xc.s[j]);
        o1.s[j] = f2bf(x1 * C.f[j] - x2 * S.f[j]);
        o2.s[j] = f2bf(x2 * C.f[j] + x1 * S.f[j]);
      }
      size_t dst = (((size_t)b * 8 + h) * 3072 + pos) * 64 + d8 * 8;
      *(uint4*)(kr + dst) = o1.v;
      *(uint4*)(kr + dst + 32) = o2.v;
    }
    return;
  }
  // V transpose -> vt [B][HKV][64][3072]
  const int b2 = bid - 2304;
  const int xt = b2 & 15;
  const int y = b2 >> 4;
  const int layer = y >> 4, b = (y >> 3) & 1, h = y & 7;
  const int t0 = xt * 64;
  {
    const int p = tid >> 2, dc = (tid & 3) * 16;
    const u16* src = qkvb + (size_t)(b * 1024 + t0 + p) * 6144 + layer * 2048 + 1536 + h * 64 + dc;
    U8 u0, u1;
    u0.v = *(const uint4*)(src);
    u1.v = *(const uint4*)(src + 8);
#pragma unroll
    for (int j = 0; j < 8; j++) { T[dc + j][p] = u0.s[j]; T[dc + 8 + j][p] = u1.s[j]; }
  }
  __syncthreads();
  {
    const int d = tid >> 2, pc = (tid & 3) * 16;
    u16* dst = vtg + ((size_t)((b * 8 + h) * 64 + d)) * 3072 + layer * 1024 + t0 + pc;
    *(uint4*)(dst) = *(const uint4*)(&T[d][pc]);
    *(uint4*)(dst + 8) = *(const uint4*)(&T[d][pc + 8]);
  }
}

// ---------------- attention v5: 32-key tiles, SMALL LDS (~14.8 KB -> 4+ blocks/CU).
// S^T orientation (r4); per-wave P region reused across nt-phases (wave-internal
// LDS ordering); V-frags pre-read to regs so nt phases share them; even chunk
// splits (halves/thirds of actual tile count) for load balance; XCD swizzle.
__global__ __launch_bounds__(256) void attn_v5(
    const u16* __restrict__ qr, const u16* __restrict__ kr,
    const u16* __restrict__ vt, float* __restrict__ obS,
    float* __restrict__ lbufp) {
  __shared__ u16 Kt[32][72];      // [key(32)][d]       4608 B
  __shared__ u16 Vtt[64][40];     // [d][key(32)]       5120 B
  __shared__ u16 Pw[4][16][40];   // per-wave P / epilogue scratch  5120 B
  const unsigned flat = blockIdx.x;
  const int bhz = (int)((flat >> 6) * 8 + (flat & 7));  // same (bh,z) -> same XCD
  const int qtile = 7 - (int)((flat >> 3) & 7);         // heavy q-tiles first
  const int z = bhz >> 5;
  const int bh = bhz & 31;
  const int lay = (z == 5) ? 0 : ((z == 0 || z == 4) ? 1 : 2);
  const int n = lay * 32 + qtile * 4 + 4;   // total 32-key tiles for this (lay,qtile)
  int kt0, kt1;
  if (lay == 0) { kt0 = 0; kt1 = n; }
  else if (lay == 1) { int hf = n >> 1; kt0 = (z == 0) ? 0 : hf; kt1 = (z == 0) ? hf : n; }
  else {
    int t1 = n / 3, t2 = (2 * n) / 3;
    kt0 = (z == 1) ? 0 : ((z == 2) ? t1 : t2);
    kt1 = (z == 1) ? t1 : ((z == 2) ? t2 : n);
  }
  const int maskkt = lay * 32 + qtile * 4;  // tiles >= this need elementwise mask
  const int b = bh >> 4, h = bh & 15, hk = h >> 1;
  const int tid = threadIdx.x, wave = tid >> 6, lane = tid & 63;
  const int quad = lane >> 4, l16 = lane & 15;
  const int qeffbase = lay * 1024 + qtile * 128 + wave * 32;
  const u16* qpb = qr + ((((size_t)lay * 2 + b) * 16 + h) * 1024
                         + qtile * 128 + wave * 32 + l16) * 64 + quad * 8;
  short8 qf[2][2];
  qf[0][0] = *(const short8*)(qpb);
  qf[0][1] = *(const short8*)(qpb + 32);
  qf[1][0] = *(const short8*)(qpb + 1024);
  qf[1][1] = *(const short8*)(qpb + 1056);
  const short8 ones = {16256, 16256, 16256, 16256, 16256, 16256, 16256, 16256};
  floatx4 oacc[2][4];
#pragma unroll
  for (int nt = 0; nt < 2; nt++)
#pragma unroll
    for (int dt = 0; dt < 4; dt++) { oacc[nt][dt][0] = 0.f; oacc[nt][dt][1] = 0.f; oacc[nt][dt][2] = 0.f; oacc[nt][dt][3] = 0.f; }
  floatx4 lacc[2];
  lacc[0][0] = 0.f; lacc[0][1] = 0.f; lacc[0][2] = 0.f; lacc[0][3] = 0.f;
  lacc[1] = lacc[0];
  // staging coords: Kt 32 rows x 64 cols (8 thr/row); Vtt 64 rows x 32 cols (4 thr/row)
  const int ksr = tid >> 3, ksc = (tid & 7) * 8;
  const int vdr = tid >> 2, vdc = (tid & 3) * 8;
  const u16* kp = kr + ((size_t)(b * 8 + hk) * 3072 + kt0 * 32 + ksr) * 64 + ksc;
  const u16* vp = vt + ((size_t)(b * 8 + hk) * 64 + vdr) * 3072 + kt0 * 32 + vdc;
  uint4 kA = *(const uint4*)kp;   // prime prefetch
  uint4 vA = *(const uint4*)vp;
  for (int kt = kt0; kt < kt1; kt++) {
    kp += 2048; vp += 32;
    __syncthreads();
    *(uint4*)(&Kt[ksr][ksc])  = kA;
    *(uint4*)(&Vtt[vdr][vdc]) = vA;
    if (kt + 1 < kt1) { kA = *(const uint4*)kp; vA = *(const uint4*)vp; }
    __syncthreads();
    const bool needmask = (kt >= maskkt);
    // S^T = K Q^T for both nt; exp+mask+pack kept in regs
    uint2 pk[2][2];  // [mt][nt]
#pragma unroll
    for (int mt = 0; mt < 2; mt++) {
      short8 kfa = *(const short8*)(&Kt[mt * 16 + l16][quad * 8]);
      short8 kfb = *(const short8*)(&Kt[mt * 16 + l16][32 + quad * 8]);
      const int keyb = kt * 32 + mt * 16 + quad * 4;
#pragma unroll
      for (int nt = 0; nt < 2; nt++) {
        floatx4 s; s[0] = 0.f; s[1] = 0.f; s[2] = 0.f; s[3] = 0.f;
        s = MFMA16(kfa, qf[nt][0], s);
        s = MFMA16(kfb, qf[nt][1], s);
        float p0 = __expf(s[0]), p1 = __expf(s[1]);
        float p2 = __expf(s[2]), p3 = __expf(s[3]);
        if (needmask) {
          int qpos = qeffbase + nt * 16 + l16;
          if (keyb + 0 > qpos) p0 = 0.f;
          if (keyb + 1 > qpos) p1 = 0.f;
          if (keyb + 2 > qpos) p2 = 0.f;
          if (keyb + 3 > qpos) p3 = 0.f;
        }
        pk[mt][nt].x = packbf(p0, p1);
        pk[mt][nt].y = packbf(p2, p3);
      }
    }
    // pre-read V frags (shared across nt phases)
    short8 vf[4];
#pragma unroll
    for (int dt = 0; dt < 4; dt++)
      vf[dt] = *(const short8*)(&Vtt[dt * 16 + l16][quad * 8]);
    // per-nt phase: P -> per-wave LDS slice -> B-operand; O^T += V^T P; l += sums
#pragma unroll
    for (int nt = 0; nt < 2; nt++) {
      *(uint2*)(&Pw[wave][l16][quad * 4])      = pk[0][nt];
      *(uint2*)(&Pw[wave][l16][16 + quad * 4]) = pk[1][nt];
      short8 pf = *(const short8*)(&Pw[wave][l16][quad * 8]);
      lacc[nt] = MFMA16(ones, pf, lacc[nt]);
#pragma unroll
      for (int dt = 0; dt < 4; dt++)
        oacc[nt][dt] = MFMA16(vf[dt], pf, oacc[nt][dt]);
    }
  }
  // epilogue: O^T (d,t) -> row-major [t][d] via the per-wave Pw scratch (1280 B)
  float* Pf = (float*)(&Pw[wave][0][0]);
  const int tt = lane >> 2, dd = (lane & 3) << 2;
#pragma unroll
  for (int nt = 0; nt < 2; nt++) {
    int t = qtile * 128 + wave * 32 + nt * 16 + l16;
    if (quad == 0)
      lbufp[((size_t)z * 2048 + b * 1024 + t) * 16 + h] = lacc[nt][0];
    int t2 = qtile * 128 + wave * 32 + nt * 16 + tt;
    float* orow = obS + ((size_t)(z * 2 + b) * 1024 + t2) * 1024 + h * 64 + dd;
#pragma unroll
    for (int dt = 0; dt < 4; dt++) {
      *(floatx4*)(&Pf[l16 * 20 + quad * 4]) = oacc[nt][dt];   // [t][d] tile
      floatx4 val = *(const floatx4*)(&Pf[tt * 20 + dd]);     // wave in-order
      *(floatx4*)(orow + dt * 16) = val;
    }
  }
}

// ---------------- fused: slot-sum (coalesced rows), /l, rmsnorm chain
__device__ __forceinline__ float block_sum(float v, float* red) {
  v += __shfl_xor(v, 32); v += __shfl_xor(v, 16); v += __shfl_xor(v, 8);
  v += __shfl_xor(v, 4);  v += __shfl_xor(v, 2);  v += __shfl_xor(v, 1);
  __syncthreads();
  if ((threadIdx.x & 63) == 0) red[threadIdx.x >> 6] = v;
  __syncthreads();
  return red[0] + red[1] + red[2] + red[3];
}

__global__ __launch_bounds__(256) void fused_norm(
    const float* __restrict__ obS, const float* __restrict__ lbufp,
    const float* __restrict__ x, const float* __restrict__ lnw,
    const float* __restrict__ lwbuf, const float* __restrict__ flnw,
    const float* __restrict__ alphap, u16* __restrict__ y) {
  __shared__ float red[4];
  const int row = blockIdx.x, tid = threadIdx.x;  // row = b*1024+t
  float a[4] = {0.f, 0.f, 0.f, 0.f};
  const int nsl[3] = {1, 2, 3};
  const int sl[3][3] = {{5, 0, 0}, {0, 4, 0}, {1, 2, 3}};
#pragma unroll
  for (int l = 0; l < 3; l++) {
    float o0 = 0.f, o1 = 0.f, o2 = 0.f, o3 = 0.f, ls = 0.f;
#pragma unroll
    for (int si = 0; si < 3; si++) {
      if (si >= nsl[l]) break;
      int z = sl[l][si];
      float4 v = ((const float4*)(obS + ((size_t)z * 2048 + row) * 1024))[tid];
      o0 += v.x; o1 += v.y; o2 += v.z; o3 += v.w;
      ls += lbufp[((size_t)z * 2048 + row) * 16 + (tid >> 4)];
    }
    float linv = 1.f / ls;
    float v0 = o0 * linv, v1 = o1 * linv, v2 = o2 * linv, v3 = o3 * linv;
    float ss = v0 * v0 + v1 * v1 + v2 * v2 + v3 * v3;
    ss = block_sum(ss, red);
    float rstd = rsqrtf(ss * (1.f / 1024.f) + 1e-5f);
    float lw = lwbuf[l];
    float4 w = ((const float4*)(lnw + (size_t)l * 1024))[tid];
    a[0] += v0 * rstd * w.x * lw;
    a[1] += v1 * rstd * w.y * lw;
    a[2] += v2 * rstd * w.z * lw;
    a[3] += v3 * rstd * w.w * lw;
  }
  const float aa = alphap[0];
  float4 xv = ((const float4*)(x + (size_t)row * 1024))[tid];
  float v0 = a[0] + aa * xv.x, v1 = a[1] + aa * xv.y;
  float v2 = a[2] + aa * xv.z, v3 = a[3] + aa * xv.w;
  float ss = v0 * v0 + v1 * v1 + v2 * v2 + v3 * v3;
  ss = block_sum(ss, red);
  float rstd = rsqrtf(ss * (1.f / 1024.f) + 1e-5f);
  float4 fw = ((const float4*)flnw)[tid];
  ushort4 o;
  o.x = f2bf(v0 * rstd * fw.x); o.y = f2bf(v1 * rstd * fw.y);
  o.z = f2bf(v2 * rstd * fw.z); o.w = f2bf(v3 * rstd * fw.w);
  ((ushort4*)(y + (size_t)row * 1024))[tid] = o;
}

extern "C" void kernel_launch(void* const* d_in, const int* in_sizes, int n_in,
                              void* d_out, int out_size, void* d_ws, size_t ws_size,
                              hipStream_t stream) {
  const float* x     = (const float*)d_in[0];
  const float* cosb  = (const float*)d_in[1];
  const float* sinb  = (const float*)d_in[2];
  const float* qw    = (const float*)d_in[3];
  const float* kw    = (const float*)d_in[4];
  const float* vw    = (const float*)d_in[5];
  const float* lnw   = (const float*)d_in[6];
  const float* lam   = (const float*)d_in[7];
  const float* outw  = (const float*)d_in[8];
  const float* flnw  = (const float*)d_in[9];
  const float* alphap= (const float*)d_in[10];
  float* out = (float*)d_out;
  char* ws = (char*)d_ws;
  // workspace (~82.6 MB). Region [0,48MB) is time-shared:
  //   phase 1: xb [0,4M) + wcat [4M,16M) + qkvb [16M,40M)
  //   phase 2: obS [0,48M)  [z][b][t][h*64+d] fp32 slots
  u16*   xb    = (u16*)  (ws + 0);          //  4 MB
  u16*   wcat  = (u16*)  (ws + 4194304);    // 12 MB
  u16*   qkvb  = (u16*)  (ws + 16777216);   // 24 MB
  float* obS   = (float*)(ws + 0);          // 48 MB
  u16*   outwb = (u16*)  (ws + 50331648);   //  2 MB
  float* lwbuf = (float*)(ws + 52428800);   //  1 KB
  u16*   qr    = (u16*)  (ws + 52429824);   // 12 MB  [3][2][16][1024][64]
  u16*   kr    = (u16*)  (ws + 65012736);   //  6 MB  [2][8][3072][64]
  u16*   vt    = (u16*)  (ws + 71304192);   //  6 MB  [2][8][64][3072]
  float* lbufp = (float*)(ws + 77595648);   // 768 KB [6][2048][16]
  u16*   yb    = (u16*)  (ws + 78382080);   //  4 MB

  prep_kernel<<<9216, 256, 0, stream>>>(x, qw, kw, vw, outw, lam, xb, wcat, outwb, lwbuf);
  gemm128<<<768, 256, 0, stream>>>(xb, wcat, qkvb, 6144, 1024, 1);
  reshape_kernel<<<3072, 256, 0, stream>>>(qkvb, cosb, sinb, qr, kr, vt);
  attn_v5<<<1536, 256, 0, stream>>>(qr, kr, vt, obS, lbufp);
  fused_norm<<<2048, 256, 0, stream>>>(obS, lbufp, x, lnw, lwbuf, flnw, alphap, yb);
  gemm_bt<<<dim3(32, 16), 256, 0, stream>>>(yb, outwb, out, 1024, 1024);
}

// Round 8
// 252.036 us; speedup vs baseline: 1.5251x; 1.0415x over previous
//
#include <hip/hip_runtime.h>
#include <type_traits>
#include <utility>

typedef unsigned short u16;
typedef unsigned int u32;
typedef short short8 __attribute__((ext_vector_type(8)));
typedef __bf16 bf16x8 __attribute__((ext_vector_type(8)));
typedef float floatx4 __attribute__((ext_vector_type(4)));

// ---- MFMA wrapper robust to either builtin signature (short8 vs v8bf16) ----
template <typename V, typename = void> struct MfmaTakes : std::false_type {};
template <typename V>
struct MfmaTakes<V, std::void_t<decltype(__builtin_amdgcn_mfma_f32_16x16x32_bf16(
    std::declval<V>(), std::declval<V>(), std::declval<floatx4>(), 0, 0, 0))>>
    : std::true_type {};

template <typename V>
__device__ __forceinline__ floatx4 mfma_impl(V a, V b, floatx4 c, std::true_type) {
  return __builtin_amdgcn_mfma_f32_16x16x32_bf16(a, b, c, 0, 0, 0);
}
template <typename V>
__device__ __forceinline__ floatx4 mfma_impl(V a, V b, floatx4 c, std::false_type) {
  return __builtin_amdgcn_mfma_f32_16x16x32_bf16(
      __builtin_bit_cast(bf16x8, a), __builtin_bit_cast(bf16x8, b), c, 0, 0, 0);
}
__device__ __forceinline__ floatx4 MFMA16(short8 a, short8 b, floatx4 c) {
  return mfma_impl<short8>(a, b, c, MfmaTakes<short8>{});
}

__device__ __forceinline__ u16 f2bf(float f) {
  union { float f; unsigned u; } x; x.f = f;
  unsigned r = (x.u + 0x7fffu + ((x.u >> 16) & 1u)) >> 16;
  return (u16)r;
}
__device__ __forceinline__ float bf2f(u16 v) {
  union { unsigned u; float f; } x; x.u = ((unsigned)v) << 16; return x.f;
}
__device__ __forceinline__ u32 packbf(float lo, float hi) {  // truncation pack (P)
  return (__float_as_uint(hi) & 0xffff0000u) | (__float_as_uint(lo) >> 16);
}
__device__ __forceinline__ u32 pack2bf(float lo, float hi) {  // round-nearest pack
  return ((u32)f2bf(hi) << 16) | (u32)f2bf(lo);
}

// ---- async global->LDS staging (16B/lane), fallback to vector copy ----
#if defined(__has_builtin)
#if __has_builtin(__builtin_amdgcn_global_load_lds)
#define HAS_GLLDS 1
#endif
#endif
__device__ __forceinline__ void stage16(const u16* g, u16* lbase, int lane) {
#ifdef HAS_GLLDS
  __builtin_amdgcn_global_load_lds(
      (__attribute__((address_space(1))) void*)(g),
      (__attribute__((address_space(3))) void*)(lbase), 16, 0, 0);
#else
  *(uint4*)(lbase + lane * 8) = *(const uint4*)g;
#endif
}

// ---------------- prep: x->bf16, concat W->bf16, out_w->bf16, lambda weights
__global__ __launch_bounds__(256) void prep_kernel(
    const float* __restrict__ x, const float* __restrict__ qw,
    const float* __restrict__ kw, const float* __restrict__ vw,
    const float* __restrict__ outw, const float* __restrict__ lam,
    u16* __restrict__ xb, u16* __restrict__ wcat, u16* __restrict__ outwb,
    float* __restrict__ lwbuf) {
  size_t gid = (size_t)blockIdx.x * 256 + threadIdx.x;
  if (gid == 0) {
    float s0 = 1.f / (1.f + expf(-lam[0]));
    float s1 = 1.f / (1.f + expf(-lam[1]));
    float s2 = 1.f / (1.f + expf(-lam[2]));
    float mean = (s0 + s1 + s2) * (1.f / 3.f);
    float d0 = s0 - mean, d1 = s1 - mean, d2 = s2 - mean;
    float var = (d0 * d0 + d1 * d1 + d2 * d2) * (1.f / 3.f);
    float r = rsqrtf(var + 1e-5f);
    lwbuf[0] = d0 * r; lwbuf[1] = d1 * r; lwbuf[2] = d2 * r;
  }
  if (gid < 524288) {
    float4 v = ((const float4*)x)[gid];
    ushort4 o; o.x = f2bf(v.x); o.y = f2bf(v.y); o.z = f2bf(v.z); o.w = f2bf(v.w);
    ((ushort4*)xb)[gid] = o;
    return;
  }
  size_t g2 = gid - 524288;
  if (g2 < 1572864) {  // wcat rows: [layer][q(1024)|k(512)|v(512)] x 1024 cols
    int col4 = (int)(g2 & 255);
    int n = (int)(g2 >> 8);
    int layer = n >> 11, r = n & 2047;
    const float* srcrow;
    if (r < 1024) srcrow = qw + ((size_t)(layer * 1024 + r) << 10);
    else if (r < 1536) srcrow = kw + ((size_t)(layer * 512 + (r - 1024)) << 10);
    else srcrow = vw + ((size_t)(layer * 512 + (r - 1536)) << 10);
    float4 v = ((const float4*)srcrow)[col4];
    ushort4 o; o.x = f2bf(v.x); o.y = f2bf(v.y); o.z = f2bf(v.z); o.w = f2bf(v.w);
    ((ushort4*)wcat)[g2] = o;
    return;
  }
  size_t g3 = g2 - 1572864;
  if (g3 < 262144) {
    float4 v = ((const float4*)outw)[g3];
    ushort4 o; o.x = f2bf(v.x); o.y = f2bf(v.y); o.z = f2bf(v.z); o.w = f2bf(v.w);
    ((ushort4*)outwb)[g3] = o;
  }
}

// ---------------- fused QKV GEMM: 128x128 tile + in-epilogue RoPE/scatter.
// Each wave's 64 cols = exactly one head (both rotation halves in-register:
// d = ni*16+l16, pair (ni, ni+2)). Writes qr/kr/vt directly -> no qkv buffer,
// no reshape kernel.
__global__ __launch_bounds__(256) void gemm_qkv(
    const u16* __restrict__ A, const u16* __restrict__ Bw,
    const float* __restrict__ cosb, const float* __restrict__ sinb,
    u16* __restrict__ qr, u16* __restrict__ kr, u16* __restrict__ vt) {
  __shared__ u16 As[128][64];
  __shared__ u16 Bs[128][64];
  const unsigned flat = blockIdx.x;
  const int bm = (flat >> 3) & 15;
  const int bn = ((flat >> 7) << 3) + (flat & 7);  // same bn -> same XCD
  const int tid = threadIdx.x;
  const int wave = tid >> 6, lane = tid & 63;
  const int quad = lane >> 4, l16 = lane & 15;
  const int wm = wave & 1, wn = wave >> 1;
  const int srow = lane >> 3, skc = (lane & 7) * 8;
  floatx4 acc[4][4];
#pragma unroll
  for (int i = 0; i < 4; i++)
#pragma unroll
    for (int j = 0; j < 4; j++) { acc[i][j][0] = 0.f; acc[i][j][1] = 0.f; acc[i][j][2] = 0.f; acc[i][j][3] = 0.f; }
  const u16* Abase = A + (size_t)(bm * 128) * 1024;
  const u16* Bbase = Bw + (size_t)(bn * 128) * 1024;
  for (int k0 = 0; k0 < 1024; k0 += 64) {
    __syncthreads();
#pragma unroll
    for (int i = 0; i < 4; i++) {
      int ch = wave * 4 + i;
      stage16(Abase + (size_t)(ch * 8 + srow) * 1024 + k0 + skc, &As[ch * 8][0], lane);
      stage16(Bbase + (size_t)(ch * 8 + srow) * 1024 + k0 + skc, &Bs[ch * 8][0], lane);
    }
    __syncthreads();
#pragma unroll
    for (int kf = 0; kf < 2; kf++) {
      short8 af[4], bf[4];
#pragma unroll
      for (int mi = 0; mi < 4; mi++)
        af[mi] = *(const short8*)(&As[wm * 64 + mi * 16 + l16][kf * 32 + quad * 8]);
#pragma unroll
      for (int ni = 0; ni < 4; ni++)
        bf[ni] = *(const short8*)(&Bs[wn * 64 + ni * 16 + l16][kf * 32 + quad * 8]);
#pragma unroll
      for (int mi = 0; mi < 4; mi++)
#pragma unroll
        for (int ni = 0; ni < 4; ni++)
          acc[mi][ni] = MFMA16(af[mi], bf[ni], acc[mi][ni]);
    }
  }
  // ---- fused epilogue (wave-uniform branches) ----
  const int f0 = bn * 128 + wn * 64;   // wave's feature base
  const int lay = f0 >> 11;
  const int r0 = f0 & 2047;            // multiple of 64 -> type/head uniform
  const int mrow0 = bm * 128 + wm * 64;
  if (r0 < 1024) {                     // ---- Q: RoPE(pos=t) * 0.125
    const int h = r0 >> 6;
#pragma unroll
    for (int mi = 0; mi < 4; mi++)
#pragma unroll
      for (int rr = 0; rr < 4; rr++) {
        int m = mrow0 + mi * 16 + quad * 4 + rr;
        int b = m >> 10, t = m & 1023;
        const float* cp = cosb + (size_t)t * 32;
        const float* sp = sinb + (size_t)t * 32;
        float c0 = cp[l16], s0 = sp[l16];
        float c1 = cp[16 + l16], s1 = sp[16 + l16];
        float x10 = acc[mi][0][rr], x20 = acc[mi][2][rr];
        float x11 = acc[mi][1][rr], x21 = acc[mi][3][rr];
        u16* row = qr + ((((size_t)lay * 2 + b) * 16 + h) * 1024 + t) * 64;
        row[l16]      = f2bf((x10 * c0 - x20 * s0) * 0.125f);
        row[16 + l16] = f2bf((x11 * c1 - x21 * s1) * 0.125f);
        row[32 + l16] = f2bf((x20 * c0 + x10 * s0) * 0.125f);
        row[48 + l16] = f2bf((x21 * c1 + x11 * s1) * 0.125f);
      }
  } else if (r0 < 1536) {              // ---- K: RoPE(pos=lay*1024+t)
    const int hk = (r0 - 1024) >> 6;
#pragma unroll
    for (int mi = 0; mi < 4; mi++)
#pragma unroll
      for (int rr = 0; rr < 4; rr++) {
        int m = mrow0 + mi * 16 + quad * 4 + rr;
        int b = m >> 10, t = m & 1023;
        int pos = lay * 1024 + t;
        const float* cp = cosb + (size_t)pos * 32;
        const float* sp = sinb + (size_t)pos * 32;
        float c0 = cp[l16], s0 = sp[l16];
        float c1 = cp[16 + l16], s1 = sp[16 + l16];
        float x10 = acc[mi][0][rr], x20 = acc[mi][2][rr];
        float x11 = acc[mi][1][rr], x21 = acc[mi][3][rr];
        u16* row = kr + (((size_t)(b * 8 + hk)) * 3072 + pos) * 64;
        row[l16]      = f2bf(x10 * c0 - x20 * s0);
        row[16 + l16] = f2bf(x11 * c1 - x21 * s1);
        row[32 + l16] = f2bf(x20 * c0 + x10 * s0);
        row[48 + l16] = f2bf(x21 * c1 + x11 * s1);
      }
  } else {                             // ---- V: transposed store [d][pos], 8B packs
    const int hv = (r0 - 1536) >> 6;
#pragma unroll
    for (int mi = 0; mi < 4; mi++) {
      int m0 = mrow0 + mi * 16 + quad * 4;
      int b = m0 >> 10;
      int pos0 = lay * 1024 + (m0 & 1023);
      u16* colbase = vt + ((size_t)(b * 8 + hv) * 64) * 3072 + pos0;
#pragma unroll
      for (int ni = 0; ni < 4; ni++) {
        int d = ni * 16 + l16;
        uint2 st;
        st.x = pack2bf(acc[mi][ni][0], acc[mi][ni][1]);
        st.y = pack2bf(acc[mi][ni][2], acc[mi][ni][3]);
        *(uint2*)(colbase + (size_t)d * 3072) = st;
      }
    }
  }
}

// ---------------- small GEMM (64x64 tile) for the out-projection
__global__ __launch_bounds__(256) void gemm_bt(
    const u16* __restrict__ A, const u16* __restrict__ Bw,
    float* __restrict__ C, int N, int K) {
  __shared__ u16 As[64][72];
  __shared__ u16 Bs[64][72];
  const int bm = blockIdx.x, bn = blockIdx.y;
  const int tid = threadIdx.x;
  const int wave = tid >> 6, lane = tid & 63;
  const int quad = lane >> 4, l16 = lane & 15;
  const int lr = tid >> 2, lc = (tid & 3) << 4;
  floatx4 acc[4];
#pragma unroll
  for (int i = 0; i < 4; i++) { acc[i][0] = 0.f; acc[i][1] = 0.f; acc[i][2] = 0.f; acc[i][3] = 0.f; }
  const u16* Arow = A + (size_t)(bm * 64 + lr) * K;
  const u16* Brow = Bw + (size_t)(bn * 64 + lr) * K;
  for (int k0 = 0; k0 < K; k0 += 64) {
    __syncthreads();
    *(uint4*)(&As[lr][lc])     = *(const uint4*)(Arow + k0 + lc);
    *(uint4*)(&As[lr][lc + 8]) = *(const uint4*)(Arow + k0 + lc + 8);
    *(uint4*)(&Bs[lr][lc])     = *(const uint4*)(Brow + k0 + lc);
    *(uint4*)(&Bs[lr][lc + 8]) = *(const uint4*)(Brow + k0 + lc + 8);
    __syncthreads();
    const int mrow = wave * 16 + l16;
    short8 a0 = *(const short8*)(&As[mrow][quad * 8]);
    short8 a1 = *(const short8*)(&As[mrow][32 + quad * 8]);
#pragma unroll
    for (int ns = 0; ns < 4; ns++) {
      short8 b0 = *(const short8*)(&Bs[ns * 16 + l16][quad * 8]);
      short8 b1 = *(const short8*)(&Bs[ns * 16 + l16][32 + quad * 8]);
      acc[ns] = MFMA16(a0, b0, acc[ns]);
      acc[ns] = MFMA16(a1, b1, acc[ns]);
    }
  }
#pragma unroll
  for (int ns = 0; ns < 4; ns++)
#pragma unroll
    for (int r = 0; r < 4; r++) {
      int row = bm * 64 + wave * 16 + quad * 4 + r;
      int col = bn * 64 + ns * 16 + l16;
      C[(size_t)row * N + col] = acc[ns][r];
    }
}

// ---------------- attention v5 (r7 structure) with bf16 obS output
__global__ __launch_bounds__(256) void attn_v5(
    const u16* __restrict__ qr, const u16* __restrict__ kr,
    const u16* __restrict__ vt, u16* __restrict__ obS,
    float* __restrict__ lbufp) {
  __shared__ u16 Kt[32][72];      // [key(32)][d]       4608 B
  __shared__ u16 Vtt[64][40];     // [d][key(32)]       5120 B
  __shared__ u16 Pw[4][16][40];   // per-wave P / epilogue scratch  5120 B
  const unsigned flat = blockIdx.x;
  const int bhz = (int)((flat >> 6) * 8 + (flat & 7));  // same (bh,z) -> same XCD
  const int qtile = 7 - (int)((flat >> 3) & 7);         // heavy q-tiles first
  const int z = bhz >> 5;
  const int bh = bhz & 31;
  const int lay = (z == 5) ? 0 : ((z == 0 || z == 4) ? 1 : 2);
  const int n = lay * 32 + qtile * 4 + 4;   // total 32-key tiles for this (lay,qtile)
  int kt0, kt1;
  if (lay == 0) { kt0 = 0; kt1 = n; }
  else if (lay == 1) { int hf = n >> 1; kt0 = (z == 0) ? 0 : hf; kt1 = (z == 0) ? hf : n; }
  else {
    int t1 = n / 3, t2 = (2 * n) / 3;
    kt0 = (z == 1) ? 0 : ((z == 2) ? t1 : t2);
    kt1 = (z == 1) ? t1 : ((z == 2) ? t2 : n);
  }
  const int maskkt = lay * 32 + qtile * 4;
  const int b = bh >> 4, h = bh & 15, hk = h >> 1;
  const int tid = threadIdx.x, wave = tid >> 6, lane = tid & 63;
  const int quad = lane >> 4, l16 = lane & 15;
  const int qeffbase = lay * 1024 + qtile * 128 + wave * 32;
  const u16* qpb = qr + ((((size_t)lay * 2 + b) * 16 + h) * 1024
                         + qtile * 128 + wave * 32 + l16) * 64 + quad * 8;
  short8 qf[2][2];
  qf[0][0] = *(const short8*)(qpb);
  qf[0][1] = *(const short8*)(qpb + 32);
  qf[1][0] = *(const short8*)(qpb + 1024);
  qf[1][1] = *(const short8*)(qpb + 1056);
  const short8 ones = {16256, 16256, 16256, 16256, 16256, 16256, 16256, 16256};
  floatx4 oacc[2][4];
#pragma unroll
  for (int nt = 0; nt < 2; nt++)
#pragma unroll
    for (int dt = 0; dt < 4; dt++) { oacc[nt][dt][0] = 0.f; oacc[nt][dt][1] = 0.f; oacc[nt][dt][2] = 0.f; oacc[nt][dt][3] = 0.f; }
  floatx4 lacc[2];
  lacc[0][0] = 0.f; lacc[0][1] = 0.f; lacc[0][2] = 0.f; lacc[0][3] = 0.f;
  lacc[1] = lacc[0];
  const int ksr = tid >> 3, ksc = (tid & 7) * 8;
  const int vdr = tid >> 2, vdc = (tid & 3) * 8;
  const u16* kp = kr + ((size_t)(b * 8 + hk) * 3072 + kt0 * 32 + ksr) * 64 + ksc;
  const u16* vp = vt + ((size_t)(b * 8 + hk) * 64 + vdr) * 3072 + kt0 * 32 + vdc;
  uint4 kA = *(const uint4*)kp;   // prime prefetch
  uint4 vA = *(const uint4*)vp;
  for (int kt = kt0; kt < kt1; kt++) {
    kp += 2048; vp += 32;
    __syncthreads();
    *(uint4*)(&Kt[ksr][ksc])  = kA;
    *(uint4*)(&Vtt[vdr][vdc]) = vA;
    if (kt + 1 < kt1) { kA = *(const uint4*)kp; vA = *(const uint4*)vp; }
    __syncthreads();
    const bool needmask = (kt >= maskkt);
    uint2 pk[2][2];  // [mt][nt]
#pragma unroll
    for (int mt = 0; mt < 2; mt++) {
      short8 kfa = *(const short8*)(&Kt[mt * 16 + l16][quad * 8]);
      short8 kfb = *(const short8*)(&Kt[mt * 16 + l16][32 + quad * 8]);
      const int keyb = kt * 32 + mt * 16 + quad * 4;
#pragma unroll
      for (int nt = 0; nt < 2; nt++) {
        floatx4 s; s[0] = 0.f; s[1] = 0.f; s[2] = 0.f; s[3] = 0.f;
        s = MFMA16(kfa, qf[nt][0], s);
        s = MFMA16(kfb, qf[nt][1], s);
        float p0 = __expf(s[0]), p1 = __expf(s[1]);
        float p2 = __expf(s[2]), p3 = __expf(s[3]);
        if (needmask) {
          int qpos = qeffbase + nt * 16 + l16;
          if (keyb + 0 > qpos) p0 = 0.f;
          if (keyb + 1 > qpos) p1 = 0.f;
          if (keyb + 2 > qpos) p2 = 0.f;
          if (keyb + 3 > qpos) p3 = 0.f;
        }
        pk[mt][nt].x = packbf(p0, p1);
        pk[mt][nt].y = packbf(p2, p3);
      }
    }
    short8 vf[4];
#pragma unroll
    for (int dt = 0; dt < 4; dt++)
      vf[dt] = *(const short8*)(&Vtt[dt * 16 + l16][quad * 8]);
#pragma unroll
    for (int nt = 0; nt < 2; nt++) {
      *(uint2*)(&Pw[wave][l16][quad * 4])      = pk[0][nt];
      *(uint2*)(&Pw[wave][l16][16 + quad * 4]) = pk[1][nt];
      short8 pf = *(const short8*)(&Pw[wave][l16][quad * 8]);
      lacc[nt] = MFMA16(ones, pf, lacc[nt]);
#pragma unroll
      for (int dt = 0; dt < 4; dt++)
        oacc[nt][dt] = MFMA16(vf[dt], pf, oacc[nt][dt]);
    }
  }
  // epilogue: O^T (d,t) -> row-major [t][d] via per-wave Pw scratch; bf16 out
  float* Pf = (float*)(&Pw[wave][0][0]);
  const int tt = lane >> 2, dd = (lane & 3) << 2;
#pragma unroll
  for (int nt = 0; nt < 2; nt++) {
    int t = qtile * 128 + wave * 32 + nt * 16 + l16;
    if (quad == 0)
      lbufp[((size_t)z * 2048 + b * 1024 + t) * 16 + h] = lacc[nt][0];
    int t2 = qtile * 128 + wave * 32 + nt * 16 + tt;
    u16* orow = obS + ((size_t)(z * 2 + b) * 1024 + t2) * 1024 + h * 64 + dd;
#pragma unroll
    for (int dt = 0; dt < 4; dt++) {
      *(floatx4*)(&Pf[l16 * 20 + quad * 4]) = oacc[nt][dt];   // [t][d] tile
      floatx4 val = *(const floatx4*)(&Pf[tt * 20 + dd]);     // wave in-order
      uint2 st; st.x = pack2bf(val[0], val[1]); st.y = pack2bf(val[2], val[3]);
      *(uint2*)(orow + dt * 16) = st;
    }
  }
}

// ---------------- fused: slot-sum (bf16 coalesced rows), /l, rmsnorm chain
__device__ __forceinline__ float block_sum(float v, float* red) {
  v += __shfl_xor(v, 32); v += __shfl_xor(v, 16); v += __shfl_xor(v, 8);
  v += __shfl_xor(v, 4);  v += __shfl_xor(v, 2);  v += __shfl_xor(v, 1);
  __syncthreads();
  if ((threadIdx.x & 63) == 0) red[threadIdx.x >> 6] = v;
  __syncthreads();
  return red[0] + red[1] + red[2] + red[3];
}

__global__ __launch_bounds__(256) void fused_norm(
    const u16* __restrict__ obS, const float* __restrict__ lbufp,
    const float* __restrict__ x, const float* __restrict__ lnw,
    const float* __restrict__ lwbuf, const float* __restrict__ flnw,
    const float* __restrict__ alphap, u16* __restrict__ y) {
  __shared__ float red[4];
  const int row = blockIdx.x, tid = threadIdx.x;  // row = b*1024+t
  float a[4] = {0.f, 0.f, 0.f, 0.f};
  const int nsl[3] = {1, 2, 3};
  const int sl[3][3] = {{5, 0, 0}, {0, 4, 0}, {1, 2, 3}};
#pragma unroll
  for (int l = 0; l < 3; l++) {
    float o0 = 0.f, o1 = 0.f, o2 = 0.f, o3 = 0.f, ls = 0.f;
#pragma unroll
    for (int si = 0; si < 3; si++) {
      if (si >= nsl[l]) break;
      int z = sl[l][si];
      uint2 v = ((const uint2*)(obS + ((size_t)z * 2048 + row) * 1024))[tid];
      o0 += bf2f((u16)(v.x & 0xffff)); o1 += bf2f((u16)(v.x >> 16));
      o2 += bf2f((u16)(v.y & 0xffff)); o3 += bf2f((u16)(v.y >> 16));
      ls += lbufp[((size_t)z * 2048 + row) * 16 + (tid >> 4)];
    }
    float linv = 1.f / ls;
    float v0 = o0 * linv, v1 = o1 * linv, v2 = o2 * linv, v3 = o3 * linv;
    float ss = v0 * v0 + v1 * v1 + v2 * v2 + v3 * v3;
    ss = block_sum(ss, red);
    float rstd = rsqrtf(ss * (1.f / 1024.f) + 1e-5f);
    float lw = lwbuf[l];
    float4 w = ((const float4*)(lnw + (size_t)l * 1024))[tid];
    a[0] += v0 * rstd * w.x * lw;
    a[1] += v1 * rstd * w.y * lw;
    a[2] += v2 * rstd * w.z * lw;
    a[3] += v3 * rstd * w.w * lw;
  }
  const float aa = alphap[0];
  float4 xv = ((const float4*)(x + (size_t)row * 1024))[tid];
  float v0 = a[0] + aa * xv.x, v1 = a[1] + aa * xv.y;
  float v2 = a[2] + aa * xv.z, v3 = a[3] + aa * xv.w;
  float ss = v0 * v0 + v1 * v1 + v2 * v2 + v3 * v3;
  ss = block_sum(ss, red);
  float rstd = rsqrtf(ss * (1.f / 1024.f) + 1e-5f);
  float4 fw = ((const float4*)flnw)[tid];
  ushort4 o;
  o.x = f2bf(v0 * rstd * fw.x); o.y = f2bf(v1 * rstd * fw.y);
  o.z = f2bf(v2 * rstd * fw.z); o.w = f2bf(v3 * rstd * fw.w);
  ((ushort4*)(y + (size_t)row * 1024))[tid] = o;
}

extern "C" void kernel_launch(void* const* d_in, const int* in_sizes, int n_in,
                              void* d_out, int out_size, void* d_ws, size_t ws_size,
                              hipStream_t stream) {
  const float* x     = (const float*)d_in[0];
  const float* cosb  = (const float*)d_in[1];
  const float* sinb  = (const float*)d_in[2];
  const float* qw    = (const float*)d_in[3];
  const float* kw    = (const float*)d_in[4];
  const float* vw    = (const float*)d_in[5];
  const float* lnw   = (const float*)d_in[6];
  const float* lam   = (const float*)d_in[7];
  const float* outw  = (const float*)d_in[8];
  const float* flnw  = (const float*)d_in[9];
  const float* alphap= (const float*)d_in[10];
  float* out = (float*)d_out;
  char* ws = (char*)d_ws;
  // workspace (~57.4 MB). Region [0,24M) is time-shared:
  //   phase 1 (prep/gemm_qkv): xb [0,4M) + wcat [4M,16M)
  //   phase 2 (attn/fused_norm): obS [0,24M)  bf16 [z][b][t][h*64+d]
  u16*   xb    = (u16*)  (ws + 0);          //  4 MB
  u16*   wcat  = (u16*)  (ws + 4194304);    // 12 MB
  u16*   obS   = (u16*)  (ws + 0);          // 24 MB (phase 2)
  u16*   outwb = (u16*)  (ws + 25165824);   //  2 MB
  float* lwbuf = (float*)(ws + 27262976);   //  1 KB
  u16*   qr    = (u16*)  (ws + 27264000);   // 12 MB  [3][2][16][1024][64]
  u16*   kr    = (u16*)  (ws + 39846912);   //  6 MB  [2][8][3072][64]
  u16*   vt    = (u16*)  (ws + 46138368);   //  6 MB  [2][8][64][3072]
  float* lbufp = (float*)(ws + 52429824);   // 768 KB [6][2048][16]
  u16*   yb    = (u16*)  (ws + 53216256);   //  4 MB

  prep_kernel<<<9216, 256, 0, stream>>>(x, qw, kw, vw, outw, lam, xb, wcat, outwb, lwbuf);
  gemm_qkv<<<768, 256, 0, stream>>>(xb, wcat, cosb, sinb, qr, kr, vt);
  attn_v5<<<1536, 256, 0, stream>>>(qr, kr, vt, obS, lbufp);
  fused_norm<<<2048, 256, 0, stream>>>(obS, lbufp, x, lnw, lwbuf, flnw, alphap, yb);
  gemm_bt<<<dim3(32, 16), 256, 0, stream>>>(yb, outwb, out, 1024, 1024);
}